// Round 5
// baseline (847.698 us; speedup 1.0000x reference)
//
#include <hip/hip_runtime.h>
#include <hip/hip_fp16.h>
#include <math.h>

#define D 128
#define PF 12

typedef _Float16 f16x8 __attribute__((ext_vector_type(8)));
typedef _Float16 f16x2 __attribute__((ext_vector_type(2)));
typedef float f32x4_t __attribute__((ext_vector_type(4)));

static __device__ __forceinline__ f16x2 h2v(__half2 h) {
    union { __half2 h; f16x2 v; } u; u.h = h; return u.v;
}
static __device__ __forceinline__ __half2 v2h(f16x2 v) {
    union { f16x2 v; __half2 h; } u; u.v = v; return u.h;
}

// ---------------- CSR build (once per call; edge_index is layer-invariant) ----------------

__global__ void hist_kernel(const int* __restrict__ edge_index, int* __restrict__ deg, int E) {
    int e = blockIdx.x * blockDim.x + threadIdx.x;
    if (e >= E) return;
    atomicAdd(&deg[edge_index[E + e]], 1);
}

__global__ void scanA_kernel(const int* __restrict__ deg, int* __restrict__ bsum, int n) {
    __shared__ int red[256];
    int b = blockIdx.x, t = threadIdx.x;
    int base = b * 1024 + t * 4;
    int s = 0;
#pragma unroll
    for (int j = 0; j < 4; ++j)
        if (base + j < n) s += deg[base + j];
    red[t] = s;
    __syncthreads();
    for (int off = 128; off > 0; off >>= 1) {
        if (t < off) red[t] += red[t + off];
        __syncthreads();
    }
    if (t == 0) bsum[b] = red[0];
}

// R19: scanB folded in — each block redundantly scans the <=256 block sums in LDS
// (nb1024 = ceil(N/1024) <= 256 for N <= 262144; here N=100K -> 98 entries).
__global__ void scanC_kernel(const int* __restrict__ deg, const int* __restrict__ bsum,
                             int nb, int* __restrict__ row_start, int* __restrict__ cursor,
                             int n) {
    __shared__ int sh[256];
    __shared__ int sb[256];
    int b = blockIdx.x, t = threadIdx.x;
    sb[t] = (t < nb) ? bsum[t] : 0;
    int base = b * 1024 + t * 4;
    int v[4];
#pragma unroll
    for (int j = 0; j < 4; ++j) v[j] = (base + j < n) ? deg[base + j] : 0;
    int p[4];
    p[0] = 0; p[1] = v[0]; p[2] = v[0] + v[1]; p[3] = v[0] + v[1] + v[2];
    int s = p[3] + v[3];
    sh[t] = s;
    __syncthreads();
    for (int off = 1; off < 256; off <<= 1) {
        int x = (t >= off) ? sh[t - off] : 0;
        int y = (t >= off) ? sb[t - off] : 0;
        __syncthreads();
        sh[t] += x;
        sb[t] += y;
        __syncthreads();
    }
    int boffb = (b == 0) ? 0 : sb[b - 1];
    int off0 = boffb + sh[t] - s;
#pragma unroll
    for (int j = 0; j < 4; ++j)
        if (base + j < n) {
            row_start[base + j] = off0 + p[j];
            cursor[base + j] = off0 + p[j];
        }
    if (base <= n - 1 && n - 1 < base + 4) row_start[n] = off0 + s;
}

// R19: scatter merged with the setup work (atom embed, ev table, Wt transpose, gstart)
// — independent index ranges, one dispatch instead of two.
__global__ void scatter_misc_kernel(const int* __restrict__ edge_index,
                                    const int* __restrict__ edge_attr,
                                    int* __restrict__ cursor, int2* __restrict__ csr, int E,
                                    const int* __restrict__ x, const float* __restrict__ atom_emb,
                                    _Float16* __restrict__ h16, int ndTotal,
                                    const float* __restrict__ bond_emb, __half2* __restrict__ evt,
                                    const float* __restrict__ conv_w, _Float16* __restrict__ wt,
                                    int wtTotal, const int* __restrict__ batch,
                                    int* __restrict__ gstart, int N, int G) {
    int idx = blockIdx.x * blockDim.x + threadIdx.x;
    if (idx < E) {
        int src = edge_index[idx];
        int dst = edge_index[E + idx];
        int pos = atomicAdd(&cursor[dst], 1);
        int a0 = edge_attr[idx * 3], a1 = edge_attr[idx * 3 + 1], a2 = edge_attr[idx * 3 + 2];
        csr[pos] = make_int2(src, a0 | (a1 << 3) | (a2 << 6));
        return;
    }
    idx -= E;
    if (idx < ndTotal) {
        int n = idx >> 7;
        int d = idx & 127;
        float acc = 0.f;
#pragma unroll
        for (int f = 0; f < 9; ++f) {
            int v = x[n * 9 + f];
            acc += atom_emb[(long long)(f * 64 + v) * D + d];
        }
        h16[idx] = (_Float16)acc;
        return;
    }
    idx -= ndTotal;
    if (idx < 512 * 64) {
        int combo = idx >> 6, j = idx & 63;
        int d0 = 2 * j;
        float ex = bond_emb[(combo & 7) * D + d0] +
                   bond_emb[(8 + ((combo >> 3) & 7)) * D + d0] +
                   bond_emb[(16 + ((combo >> 6) & 7)) * D + d0];
        float ey = bond_emb[(combo & 7) * D + d0 + 1] +
                   bond_emb[(8 + ((combo >> 3) & 7)) * D + d0 + 1] +
                   bond_emb[(16 + ((combo >> 6) & 7)) * D + d0 + 1];
        evt[idx] = __floats2half2_rn(ex, ey);
        return;
    }
    int widx = idx - 512 * 64;
    if (widx < wtTotal) {
        int l = widx >> 14;
        int rem = widx & 16383;
        int n = rem >> 7, k = rem & 127;
        wt[widx] = (_Float16)conv_w[(l << 14) + k * 128 + n];
        return;
    }
    int n = widx - wtTotal;
    if (n >= N) return;
    if (n == 0) {
        for (int g = 0; g <= batch[0]; ++g) gstart[g] = 0;
    } else {
        int b0 = batch[n - 1], b1 = batch[n];
        for (int g = b0 + 1; g <= b1; ++g) gstart[g] = n;
    }
    if (n == N - 1) {
        for (int g = batch[N - 1] + 1; g <= G; ++g) gstart[g] = N;
    }
}

// ---------------- model kernels ----------------

// R19: BN stats now accumulated by fused_layer via atomicAdd into acc4[4][256]
// (4 copies by blockIdx&3 to spread per-address contention; plain atomic
// accumulation like hist — NOT a cross-block ordering dependence). This kernel is
// the only remaining BN dispatch: 1 block, 128 threads, reads 4KB, folds coeffs.
// Cross-dispatch visibility is the HSA dispatch-boundary acquire/release (same
// mechanism the aArr/bArr flow already relied on).
__global__ void bn_finalize_kernel(const float* __restrict__ acc4,
                                   const float* __restrict__ gamma,
                                   const float* __restrict__ bnbeta, float invN,
                                   float* __restrict__ aArr, float* __restrict__ bArr) {
    int t = threadIdx.x;  // 128
    float s1 = acc4[t] + acc4[256 + t] + acc4[512 + t] + acc4[768 + t];
    float s2 = acc4[128 + t] + acc4[384 + t] + acc4[640 + t] + acc4[896 + t];
    float mean = s1 * invN;
    float var = s2 * invN - mean * mean;
    float a = rsqrtf(var + 1e-5f) * gamma[t];
    aArr[t] = a;
    bArr[t] = bnbeta[t] - mean * a;
}

// R11 structure (the measured optimum of this design family). Post-mortems:
// - R15 PF=16 spilled (launch_bounds(128,8) = 64 VGPR cap; WRITE +25MB scratch).
// - R16 exp2f regressed: plain exp2f goes through OCML fixup code, not bare v_exp
//   (VALUBusy 52->58). __expf IS the fast path. KEEP __expf.
// - R16 32-bit gather idx regressed: srcp is wave-uniform (readlane->SGPR); the
//   (size_t) form lets addressing stay SCALAR (saddr+loop-invariant voffset). KEEP size_t.
// - R17 (kept): eps folded out of edge loop (softmax-invariant), __fdividef at close.
// - R18/R19: edge loop FROZEN; R19 swaps the 256-float partial write for atomicAdd
//   into acc4 (removes 6.4MB/layer write traffic + the bn_stage1 dispatch).
// Per-layer fused, 128 threads / 2 waves / 16-row tile: dst-centric softmax agg
// (f16 gathers, packed-f16 inline BN, 12-deep pipeline, double-buffered csr chunks
// [FIFO vmcnt], register self rows, write-only row close) -> f16 y-tile in LDS ->
// ONE barrier -> column-split MFMA f16 16x128 @ 128x128 (+bias, +f16 residual,
// fp32 acc) -> f16 output + atomic BN-stat accumulation.
// segment-max skipped: softmax shift-invariant, msg bounded -> exp can't overflow fp32.
// NOTE (R9): NO global work-stealing counters on multi-XCD CDNA.
__global__ __launch_bounds__(128, 8) void fused_layer_kernel(
        const __half2* __restrict__ h16c,
        const float* __restrict__ aArr, const float* __restrict__ bArr, int applyBN,
        const float* __restrict__ ts, int l,
        const int* __restrict__ row_start, const int2* __restrict__ csr,
        const __half2* __restrict__ evt,
        const _Float16* __restrict__ wt, const float* __restrict__ bias,
        int residual, _Float16* __restrict__ h16out,
        float* __restrict__ accL, int N) {
    // y tile: 16 rows x 136 halves = 4352 B; stats scratch needs 8 KB -> size 8192
    __shared__ __align__(16) char smem[8192];
    _Float16* yh = (_Float16*)smem;
    __half2* tile2 = (__half2*)smem;  // half2 view: row stride 68

    int t = threadIdx.x;
    int row0 = blockIdx.x * 16;
    int wave = t >> 6;
    int lane = t & 63;
    float tsl = ts[l];
    int a = row0 + wave * 8;  // wave owns rows a..a+7

    f16x2 zerov = (f16x2)(_Float16)0;
    f16x2 bnA2 = zerov, bnB2 = zerov;
    if (applyBN) {
        float2 af = ((const float2*)aArr)[lane];
        float2 bf = ((const float2*)bArr)[lane];
        bnA2[0] = (_Float16)af.x; bnA2[1] = (_Float16)af.y;
        bnB2[0] = (_Float16)bf.x; bnB2[1] = (_Float16)bf.y;
    }
    __half2 zero2 = v2h(zerov);

    // issue rsv load, then 8 self-row gathers (FIFO vmcnt: readlane below waits only rsv)
    int rsv = row_start[min(a + min(lane, 8), N)];
    __half2 hsv0 = zero2, hsv1 = zero2, hsv2 = zero2, hsv3 = zero2;
    __half2 hsv4 = zero2, hsv5 = zero2, hsv6 = zero2, hsv7 = zero2;
    if (a + 0 < N) hsv0 = h16c[(size_t)(a + 0) * 64 + lane];
    if (a + 1 < N) hsv1 = h16c[(size_t)(a + 1) * 64 + lane];
    if (a + 2 < N) hsv2 = h16c[(size_t)(a + 2) * 64 + lane];
    if (a + 3 < N) hsv3 = h16c[(size_t)(a + 3) * 64 + lane];
    if (a + 4 < N) hsv4 = h16c[(size_t)(a + 4) * 64 + lane];
    if (a + 5 < N) hsv5 = h16c[(size_t)(a + 5) * 64 + lane];
    if (a + 6 < N) hsv6 = h16c[(size_t)(a + 6) * 64 + lane];
    if (a + 7 < N) hsv7 = h16c[(size_t)(a + 7) * 64 + lane];

    int s0 = __builtin_amdgcn_readlane(rsv, 0);
    int s1 = __builtin_amdgcn_readlane(rsv, 8);

    // double-buffered csr chunks: eaCur active, eaNxt in flight
    int c0 = s0;
    int2 eaCur = make_int2(0, 0), eaNxt = make_int2(0, 0);
    if (c0 + lane < s1) eaCur = csr[c0 + lane];
    if (c0 + 64 + lane < s1) eaNxt = csr[c0 + 64 + lane];

    __half2 hvS[PF], evS[PF];
#pragma unroll
    for (int k = 0; k < PF; ++k) {
        int pp = s0 + k;
        if (pp < s1) {  // q = k < 64: always chunk 0
            int srcp = __builtin_amdgcn_readlane(eaCur.x, k);
            int cbp = __builtin_amdgcn_readlane(eaCur.y, k);
            hvS[k] = h16c[(size_t)srcp * 64 + lane];
            evS[k] = evt[(size_t)cbp * 64 + lane];
        }
    }

    float accwx = 0.f, accwy = 0.f, accmx = 0.f, accmy = 0.f;
    int cur = 0;
    int nend = __builtin_amdgcn_readlane(rsv, 1);

    // eps folded: weights lose the exp(eps*t) factor (softmax-invariant); aggregated
    // message regains +eps once here (sum(alpha)=1). Empty rows: +1e-7 abs, negligible.
#define CLOSE_ROW()                                                           \
    {                                                                         \
        __half2 hh;                                                           \
        switch (cur) {                                                        \
            case 0: hh = hsv0; break; case 1: hh = hsv1; break;               \
            case 2: hh = hsv2; break; case 3: hh = hsv3; break;               \
            case 4: hh = hsv4; break; case 5: hh = hsv5; break;               \
            case 6: hh = hsv6; break; default: hh = hsv7; break;              \
        }                                                                     \
        f16x2 hvv = h2v(hh);                                                  \
        if (applyBN)                                                          \
            hvv = __builtin_elementwise_max(hvv * bnA2 + bnB2, zerov);        \
        float2 yy;                                                            \
        yy.x = (float)hvv[0] + __fdividef(accmx, accwx + 1e-16f) + 1e-7f;     \
        yy.y = (float)hvv[1] + __fdividef(accmy, accwy + 1e-16f) + 1e-7f;     \
        tile2[(wave * 8 + cur) * 68 + lane] = __floats2half2_rn(yy.x, yy.y);  \
        accwx = accwy = accmx = accmy = 0.f;                                  \
        cur++;                                                                \
        nend = __builtin_amdgcn_readlane(rsv, min(cur + 1, 8));               \
    }

    while (cur < 8 && nend == s0) CLOSE_ROW();  // leading empty rows

    int total = s1 - s0;
    for (int it = 0; it < total; it += PF) {
#pragma unroll
        for (int k = 0; k < PF; ++k) {
            int p = s0 + it + k;
            if (p < s1) {
                f16x2 hv2 = h2v(hvS[k]);
                if (applyBN)
                    hv2 = __builtin_elementwise_max(hv2 * bnA2 + bnB2, zerov);
                f16x2 m2 = __builtin_elementwise_max(hv2 + h2v(evS[k]), zerov);
                float mx = (float)m2[0];
                float my = (float)m2[1];
                float wx = __expf(mx * tsl);
                float wy = __expf(my * tsl);
                accwx += wx; accmx = fmaf(wx, mx, accmx);
                accwy += wy; accmy = fmaf(wy, my, accmy);
                int pp = p + PF;
                if (pp < s1) {
                    if (pp >= c0 + 64) {  // rollover: eaNxt loaded ~64 edges ago, no drain
                        c0 += 64;
                        eaCur = eaNxt;
                        eaNxt = make_int2(0, 0);
                        if (c0 + 64 + lane < s1) eaNxt = csr[c0 + 64 + lane];
                    }
                    int q = pp - c0;
                    int srcp = __builtin_amdgcn_readlane(eaCur.x, q);
                    int cbp = __builtin_amdgcn_readlane(eaCur.y, q);
                    hvS[k] = h16c[(size_t)srcp * 64 + lane];
                    evS[k] = evt[(size_t)cbp * 64 + lane];
                }
                while (cur < 8 && nend == p + 1) CLOSE_ROW();
            }
        }
    }
#undef CLOSE_ROW
    __syncthreads();

    // ---- MFMA matmul: both waves read all 16 tile rows; wave w covers cols w*64.. ----
    int ln = t & 15;
    int quad = (t & 63) >> 4;
    const _Float16* h16in = (const _Float16*)h16c;

    float cs[4] = {0.f, 0.f, 0.f, 0.f};
    float cq[4] = {0.f, 0.f, 0.f, 0.f};
    const _Float16* ap = yh + ln * 136 + quad * 8;
#pragma unroll
    for (int ct = 0; ct < 4; ++ct) {
        int colg = (wave * 4 + ct) * 16 + ln;
        const _Float16* bp = wt + (size_t)colg * 128 + quad * 8;
        f32x4_t c = {0.f, 0.f, 0.f, 0.f};
#pragma unroll
        for (int kk = 0; kk < 4; ++kk) {
            f16x8 av = *(const f16x8*)(ap + kk * 32);
            f16x8 bv = *(const f16x8*)(bp + kk * 32);
            c = __builtin_amdgcn_mfma_f32_16x16x32_f16(av, bv, c, 0, 0, 0);
        }
        float bsv = bias[colg];
#pragma unroll
        for (int reg = 0; reg < 4; ++reg) {
            int r = row0 + quad * 4 + reg;
            if (r < N) {
                long long off = (long long)r * D + colg;
                float o = c[reg] + bsv;
                if (residual) o += (float)h16in[off];
                h16out[off] = (_Float16)o;
                cs[ct] += o; cq[ct] += o * o;
            }
        }
    }

    // ---- BN-stat partials (reuse smem; y tile dead) -> atomic accumulate ----
    __syncthreads();
    float* stats = (float*)smem;
    int grp = wave * 4 + quad;  // 0..7
#pragma unroll
    for (int ct = 0; ct < 4; ++ct) {
        int colg = (wave * 4 + ct) * 16 + ln;
        stats[grp * 256 + colg] = cs[ct];
        stats[grp * 256 + 128 + colg] = cq[ct];
    }
    __syncthreads();
    float ssumA = 0.f, ssumB = 0.f;
#pragma unroll
    for (int g = 0; g < 8; ++g) {
        ssumA += stats[g * 256 + t];
        ssumB += stats[g * 256 + 128 + t];
    }
    int cbase = (blockIdx.x & 3) << 8;  // 4 copies to spread contention
    atomicAdd(&accL[cbase + t], ssumA);
    atomicAdd(&accL[cbase + 128 + t], ssumB);
}

// one block per graph: inline BN finalize (reads acc4, 4KB) + BN+relu, mean pool,
// linear head, sigmoid, blend with rf. half2 loads, 4 nodes/iteration.
__global__ void pool_head_kernel(const __half2* __restrict__ h16,
                                 const float* __restrict__ acc4,
                                 const float* __restrict__ gamma,
                                 const float* __restrict__ bnbeta, float invN,
                                 const int* __restrict__ gstart,
                                 const float* __restrict__ fw, const float* __restrict__ fb,
                                 const float* __restrict__ beta, const float* __restrict__ rf,
                                 float* __restrict__ out) {
    __shared__ float redx[256], redy[256];
    __shared__ float sA[128], sB[128];
    int g = blockIdx.x, t = threadIdx.x;
    if (t < 128) {
        float s1 = acc4[t] + acc4[256 + t] + acc4[512 + t] + acc4[768 + t];
        float s2 = acc4[128 + t] + acc4[384 + t] + acc4[640 + t] + acc4[896 + t];
        float mean = s1 * invN;
        float var = s2 * invN - mean * mean;
        float a = rsqrtf(var + 1e-5f) * gamma[t];
        sA[t] = a;
        sB[t] = bnbeta[t] - mean * a;
    }
    __syncthreads();
    int d2 = t & 63, sub = t >> 6;
    int s0 = gstart[g], s1 = gstart[g + 1];
    float2 a2 = make_float2(sA[2 * d2], sA[2 * d2 + 1]);
    float2 b2 = make_float2(sB[2 * d2], sB[2 * d2 + 1]);
    float ax = 0.f, ay = 0.f;
    for (int n = s0 + sub; n < s1; n += 4) {
        f16x2 v = h2v(h16[(size_t)n * 64 + d2]);
        ax += fmaxf((float)v[0] * a2.x + b2.x, 0.f);
        ay += fmaxf((float)v[1] * a2.y + b2.y, 0.f);
    }
    redx[t] = ax; redy[t] = ay;
    __syncthreads();
    if (t < 64) {
        float sx = redx[t] + redx[t + 64] + redx[t + 128] + redx[t + 192];
        float sy = redy[t] + redy[t + 64] + redy[t + 128] + redy[t + 192];
        float v = sx * fw[2 * t] + sy * fw[2 * t + 1];
#pragma unroll
        for (int off = 32; off > 0; off >>= 1) v += __shfl_down(v, off);
        if (t == 0) {
            float c = fmaxf((float)(s1 - s0), 1.f);
            float pred = v / c + fb[0];
            float sig = 1.f / (1.f + __expf(-pred));
            float bb = beta[0];
            out[g] = (1.f - bb) * sig + bb * rf[g];
        }
    }
}

static inline size_t align16(size_t x) { return (x + 15) & ~(size_t)15; }

extern "C" void kernel_launch(void* const* d_in, const int* in_sizes, int n_in,
                              void* d_out, int out_size, void* d_ws, size_t ws_size,
                              hipStream_t stream) {
    const int* x = (const int*)d_in[0];
    const int* edge_index = (const int*)d_in[1];
    const int* edge_attr = (const int*)d_in[2];
    const int* batch = (const int*)d_in[3];
    const float* rf_pred = (const float*)d_in[4];
    const float* atom_emb = (const float*)d_in[5];
    const float* bond_emb = (const float*)d_in[6];
    const float* conv_w = (const float*)d_in[7];
    const float* conv_b = (const float*)d_in[8];
    const float* ts = (const float*)d_in[9];
    const float* gammas = (const float*)d_in[10];
    const float* bn_betas = (const float*)d_in[11];
    const float* final_w = (const float*)d_in[12];
    const float* final_b = (const float*)d_in[13];
    const float* beta = (const float*)d_in[14];
    float* out = (float*)d_out;

    int N = in_sizes[0] / 9;
    int E = in_sizes[1] / 2;
    int G = in_sizes[4];
    int L = in_sizes[9];

    int nTiles = (N + 15) / 16;
    size_t ND = (size_t)N * D;
    size_t accFloats = (size_t)L * 1024;  // per layer: 4 copies x 256

    char* p = (char*)d_ws;
    _Float16* h16_a = (_Float16*)p;  p += align16(ND * 2);
    _Float16* h16_b = (_Float16*)p;  p += align16(ND * 2);
    __half2* evt = (__half2*)p;      p += align16((size_t)512 * 64 * 4);
    _Float16* wt = (_Float16*)p;     p += align16((size_t)L * 16384 * 2);
    float* aArr = (float*)p;         p += align16((size_t)D * 4);
    float* bArr = (float*)p;         p += align16((size_t)D * 4);
    int* gstart = (int*)p;           p += align16((size_t)(G + 1) * 4);
    // acc + deg contiguous: one memset zeroes both
    float* acc = (float*)p;          p += align16(accFloats * 4);
    int* deg = (int*)p;              p += align16((size_t)N * 4);
    int* row_start = (int*)p;        p += align16((size_t)(N + 1) * 4);
    int* cursor = (int*)p;           p += align16((size_t)N * 4);
    int* bsum = (int*)p;             p += align16((size_t)256 * 4);
    int2* csr = (int2*)p;            p += align16((size_t)E * 8);

    int eBlocks = (E + 255) / 256;
    int nb1024 = (N + 1023) / 1024;
    int wtTotal = L * 16384;
    int ndTotal = N * D;
    int smTotal = E + ndTotal + 512 * 64 + wtTotal + N;
    int smBlocks = (smTotal + 255) / 256;
    float invN = 1.0f / (float)N;

    // ---- CSR + atom embedding + tables + graph boundaries ----
    (void)hipMemsetAsync(acc, 0, align16(accFloats * 4) + (size_t)N * 4, stream);
    hist_kernel<<<eBlocks, 256, 0, stream>>>(edge_index, deg, E);
    scanA_kernel<<<nb1024, 256, 0, stream>>>(deg, bsum, N);
    scanC_kernel<<<nb1024, 256, 0, stream>>>(deg, bsum, nb1024, row_start, cursor, N);
    scatter_misc_kernel<<<smBlocks, 256, 0, stream>>>(edge_index, edge_attr, cursor, csr, E,
                                                      x, atom_emb, h16_a, ndTotal,
                                                      bond_emb, evt, conv_w, wt, wtTotal,
                                                      batch, gstart, N, G);

    _Float16* h16c = h16_a;
    _Float16* h16n = h16_b;
    for (int l = 0; l < L; ++l) {
        int applyBN = (l >= 1) ? 1 : 0;
        if (applyBN) {
            bn_finalize_kernel<<<1, 128, 0, stream>>>(
                acc + (size_t)(l - 1) * 1024, gammas + (size_t)(l - 1) * D,
                bn_betas + (size_t)(l - 1) * D, invN, aArr, bArr);
        }
        fused_layer_kernel<<<nTiles, 128, 0, stream>>>(
            (const __half2*)h16c, aArr, bArr, applyBN, ts, l, row_start, csr, evt,
            wt + (size_t)l * 16384, conv_b + (size_t)l * D,
            applyBN, h16n, acc + (size_t)l * 1024, N);
        _Float16* tmp16 = h16c; h16c = h16n; h16n = tmp16;
    }

    pool_head_kernel<<<G, 256, 0, stream>>>(
        (const __half2*)h16c, acc + (size_t)(L - 1) * 1024,
        gammas + (size_t)(L - 1) * D, bn_betas + (size_t)(L - 1) * D, invN,
        gstart, final_w, final_b, beta, rf_pred, out);
}

// Round 6
// 772.541 us; speedup vs baseline: 1.0973x; 1.0973x over previous
//
#include <hip/hip_runtime.h>
#include <hip/hip_fp16.h>
#include <math.h>

#define D 128
#define PF 12

typedef _Float16 f16x8 __attribute__((ext_vector_type(8)));
typedef _Float16 f16x2 __attribute__((ext_vector_type(2)));
typedef float f32x4_t __attribute__((ext_vector_type(4)));

static __device__ __forceinline__ f16x2 h2v(__half2 h) {
    union { __half2 h; f16x2 v; } u; u.h = h; return u.v;
}
static __device__ __forceinline__ __half2 v2h(f16x2 v) {
    union { f16x2 v; __half2 h; } u; u.v = v; return u.h;
}

// ---------------- CSR build (once per call; edge_index is layer-invariant) ----------------

__global__ void hist_kernel(const int* __restrict__ edge_index, int* __restrict__ deg, int E) {
    int e = blockIdx.x * blockDim.x + threadIdx.x;
    if (e >= E) return;
    atomicAdd(&deg[edge_index[E + e]], 1);
}

__global__ void scanA_kernel(const int* __restrict__ deg, int* __restrict__ bsum, int n) {
    __shared__ int red[256];
    int b = blockIdx.x, t = threadIdx.x;
    int base = b * 1024 + t * 4;
    int s = 0;
#pragma unroll
    for (int j = 0; j < 4; ++j)
        if (base + j < n) s += deg[base + j];
    red[t] = s;
    __syncthreads();
    for (int off = 128; off > 0; off >>= 1) {
        if (t < off) red[t] += red[t + off];
        __syncthreads();
    }
    if (t == 0) bsum[b] = red[0];
}

// R19: scanB folded in — each block redundantly scans the <=256 block sums in LDS
// (nb1024 = ceil(N/1024) <= 256 for N <= 262144; here N=100K -> 98 entries).
__global__ void scanC_kernel(const int* __restrict__ deg, const int* __restrict__ bsum,
                             int nb, int* __restrict__ row_start, int* __restrict__ cursor,
                             int n) {
    __shared__ int sh[256];
    __shared__ int sb[256];
    int b = blockIdx.x, t = threadIdx.x;
    sb[t] = (t < nb) ? bsum[t] : 0;
    int base = b * 1024 + t * 4;
    int v[4];
#pragma unroll
    for (int j = 0; j < 4; ++j) v[j] = (base + j < n) ? deg[base + j] : 0;
    int p[4];
    p[0] = 0; p[1] = v[0]; p[2] = v[0] + v[1]; p[3] = v[0] + v[1] + v[2];
    int s = p[3] + v[3];
    sh[t] = s;
    __syncthreads();
    for (int off = 1; off < 256; off <<= 1) {
        int x = (t >= off) ? sh[t - off] : 0;
        int y = (t >= off) ? sb[t - off] : 0;
        __syncthreads();
        sh[t] += x;
        sb[t] += y;
        __syncthreads();
    }
    int boffb = (b == 0) ? 0 : sb[b - 1];
    int off0 = boffb + sh[t] - s;
#pragma unroll
    for (int j = 0; j < 4; ++j)
        if (base + j < n) {
            row_start[base + j] = off0 + p[j];
            cursor[base + j] = off0 + p[j];
        }
    if (base <= n - 1 && n - 1 < base + 4) row_start[n] = off0 + s;
}

// R19: scatter merged with the setup work (atom embed, ev table, Wt transpose, gstart)
// — independent index ranges, one dispatch instead of two.
__global__ void scatter_misc_kernel(const int* __restrict__ edge_index,
                                    const int* __restrict__ edge_attr,
                                    int* __restrict__ cursor, int2* __restrict__ csr, int E,
                                    const int* __restrict__ x, const float* __restrict__ atom_emb,
                                    _Float16* __restrict__ h16, int ndTotal,
                                    const float* __restrict__ bond_emb, __half2* __restrict__ evt,
                                    const float* __restrict__ conv_w, _Float16* __restrict__ wt,
                                    int wtTotal, const int* __restrict__ batch,
                                    int* __restrict__ gstart, int N, int G) {
    int idx = blockIdx.x * blockDim.x + threadIdx.x;
    if (idx < E) {
        int src = edge_index[idx];
        int dst = edge_index[E + idx];
        int pos = atomicAdd(&cursor[dst], 1);
        int a0 = edge_attr[idx * 3], a1 = edge_attr[idx * 3 + 1], a2 = edge_attr[idx * 3 + 2];
        csr[pos] = make_int2(src, a0 | (a1 << 3) | (a2 << 6));
        return;
    }
    idx -= E;
    if (idx < ndTotal) {
        int n = idx >> 7;
        int d = idx & 127;
        float acc = 0.f;
#pragma unroll
        for (int f = 0; f < 9; ++f) {
            int v = x[n * 9 + f];
            acc += atom_emb[(long long)(f * 64 + v) * D + d];
        }
        h16[idx] = (_Float16)acc;
        return;
    }
    idx -= ndTotal;
    if (idx < 512 * 64) {
        int combo = idx >> 6, j = idx & 63;
        int d0 = 2 * j;
        float ex = bond_emb[(combo & 7) * D + d0] +
                   bond_emb[(8 + ((combo >> 3) & 7)) * D + d0] +
                   bond_emb[(16 + ((combo >> 6) & 7)) * D + d0];
        float ey = bond_emb[(combo & 7) * D + d0 + 1] +
                   bond_emb[(8 + ((combo >> 3) & 7)) * D + d0 + 1] +
                   bond_emb[(16 + ((combo >> 6) & 7)) * D + d0 + 1];
        evt[idx] = __floats2half2_rn(ex, ey);
        return;
    }
    int widx = idx - 512 * 64;
    if (widx < wtTotal) {
        int l = widx >> 14;
        int rem = widx & 16383;
        int n = rem >> 7, k = rem & 127;
        wt[widx] = (_Float16)conv_w[(l << 14) + k * 128 + n];
        return;
    }
    int n = widx - wtTotal;
    if (n >= N) return;
    if (n == 0) {
        for (int g = 0; g <= batch[0]; ++g) gstart[g] = 0;
    } else {
        int b0 = batch[n - 1], b1 = batch[n];
        for (int g = b0 + 1; g <= b1; ++g) gstart[g] = n;
    }
    if (n == N - 1) {
        for (int g = batch[N - 1] + 1; g <= G; ++g) gstart[g] = N;
    }
}

// ---------------- model kernels ----------------

// R20: BN reduce topology fixed. R19's per-fused-block atomics (3.2M adds onto 1024
// addrs = 1562/addr) serialized at L2 and cost +15.6us/layer. Now: fused writes
// per-block partials non-atomically (R18 proven form, full BW); this stage1 does
// coalesced column sums (256 blocks; thread t reads column t of 1KB rows) and
// atomicAdds into acc4[4][256] -> 65K atomics, 64/addr (hist-class contention).
// The finalize dispatch is GONE: consumers (next fused layer / pool_head) fold
// acc4 -> (a,b) inline (4KB read, L2-resident per XCD).
__global__ void bn_stage1_kernel(const float* __restrict__ partial, int nb,
                                 float* __restrict__ acc4) {
    int b = blockIdx.x, t = threadIdx.x;
    float s = 0.f;
    for (int r = b; r < nb; r += 256)
        s += partial[(long long)r * 256 + t];
    atomicAdd(&acc4[((b & 3) << 8) + t], s);
}

// R11 structure (the measured optimum of this design family). Post-mortems:
// - R15 PF=16 spilled (launch_bounds(128,8) = 64 VGPR cap; WRITE +25MB scratch).
// - R16 exp2f regressed: plain exp2f goes through OCML fixup code, not bare v_exp
//   (VALUBusy 52->58). __expf IS the fast path. KEEP __expf.
// - R16 32-bit gather idx regressed: srcp is wave-uniform (readlane->SGPR); the
//   (size_t) form lets addressing stay SCALAR (saddr+loop-invariant voffset). KEEP size_t.
// - R17 (kept): eps folded out of edge loop (softmax-invariant), __fdividef at close.
// - R19 post-mortem: per-block BN atomics = L2 serialization (-15.6us/layer). REVERTED.
// - R20: BN coeffs folded in PROLOGUE from acc4 (10 float2 loads + 2 rsqrt, overlapped
//   under the self-row gather latency); kills the per-layer finalize dispatch. Edge
//   loop / MFMA / close-row untouched.
// Per-layer fused, 128 threads / 2 waves / 16-row tile: dst-centric softmax agg
// (f16 gathers, packed-f16 inline BN, 12-deep pipeline, double-buffered csr chunks
// [FIFO vmcnt], register self rows, write-only row close) -> f16 y-tile in LDS ->
// ONE barrier -> column-split MFMA f16 16x128 @ 128x128 (+bias, +f16 residual,
// fp32 acc) -> f16 output + per-block BN-stat partials.
// segment-max skipped: softmax shift-invariant, msg bounded -> exp can't overflow fp32.
// NOTE (R9): NO global work-stealing counters on multi-XCD CDNA.
__global__ __launch_bounds__(128, 8) void fused_layer_kernel(
        const __half2* __restrict__ h16c,
        const float* __restrict__ accPrev, const float* __restrict__ gammaPrev,
        const float* __restrict__ betaPrev, float invN, int applyBN,
        const float* __restrict__ ts, int l,
        const int* __restrict__ row_start, const int2* __restrict__ csr,
        const __half2* __restrict__ evt,
        const _Float16* __restrict__ wt, const float* __restrict__ bias,
        int residual, _Float16* __restrict__ h16out,
        float* __restrict__ partial, int N) {
    // y tile: 16 rows x 136 halves = 4352 B; stats scratch needs 8 KB -> size 8192
    __shared__ __align__(16) char smem[8192];
    _Float16* yh = (_Float16*)smem;
    __half2* tile2 = (__half2*)smem;  // half2 view: row stride 68

    int t = threadIdx.x;
    int row0 = blockIdx.x * 16;
    int wave = t >> 6;
    int lane = t & 63;
    float tsl = ts[l];
    int a = row0 + wave * 8;  // wave owns rows a..a+7

    f16x2 zerov = (f16x2)(_Float16)0;
    __half2 zero2 = v2h(zerov);

    // issue rsv load + 8 self-row gathers FIRST; BN fold below overlaps their latency
    int rsv = row_start[min(a + min(lane, 8), N)];
    __half2 hsv0 = zero2, hsv1 = zero2, hsv2 = zero2, hsv3 = zero2;
    __half2 hsv4 = zero2, hsv5 = zero2, hsv6 = zero2, hsv7 = zero2;
    if (a + 0 < N) hsv0 = h16c[(size_t)(a + 0) * 64 + lane];
    if (a + 1 < N) hsv1 = h16c[(size_t)(a + 1) * 64 + lane];
    if (a + 2 < N) hsv2 = h16c[(size_t)(a + 2) * 64 + lane];
    if (a + 3 < N) hsv3 = h16c[(size_t)(a + 3) * 64 + lane];
    if (a + 4 < N) hsv4 = h16c[(size_t)(a + 4) * 64 + lane];
    if (a + 5 < N) hsv5 = h16c[(size_t)(a + 5) * 64 + lane];
    if (a + 6 < N) hsv6 = h16c[(size_t)(a + 6) * 64 + lane];
    if (a + 7 < N) hsv7 = h16c[(size_t)(a + 7) * 64 + lane];

    // BN coefficient fold (replaces the finalize dispatch)
    f16x2 bnA2 = zerov, bnB2 = zerov;
    if (applyBN) {
        float s1x = 0.f, s1y = 0.f, s2x = 0.f, s2y = 0.f;
#pragma unroll
        for (int c = 0; c < 4; ++c) {
            float2 u = ((const float2*)(accPrev + c * 256))[lane];
            float2 v = ((const float2*)(accPrev + c * 256 + 128))[lane];
            s1x += u.x; s1y += u.y; s2x += v.x; s2y += v.y;
        }
        float2 gm = ((const float2*)gammaPrev)[lane];
        float2 bb = ((const float2*)betaPrev)[lane];
        float meanx = s1x * invN, meany = s1y * invN;
        float varx = s2x * invN - meanx * meanx;
        float vary = s2y * invN - meany * meany;
        float ax = rsqrtf(varx + 1e-5f) * gm.x;
        float ay = rsqrtf(vary + 1e-5f) * gm.y;
        bnA2[0] = (_Float16)ax; bnA2[1] = (_Float16)ay;
        bnB2[0] = (_Float16)(bb.x - meanx * ax);
        bnB2[1] = (_Float16)(bb.y - meany * ay);
    }

    int s0 = __builtin_amdgcn_readlane(rsv, 0);
    int s1 = __builtin_amdgcn_readlane(rsv, 8);

    // double-buffered csr chunks: eaCur active, eaNxt in flight
    int c0 = s0;
    int2 eaCur = make_int2(0, 0), eaNxt = make_int2(0, 0);
    if (c0 + lane < s1) eaCur = csr[c0 + lane];
    if (c0 + 64 + lane < s1) eaNxt = csr[c0 + 64 + lane];

    __half2 hvS[PF], evS[PF];
#pragma unroll
    for (int k = 0; k < PF; ++k) {
        int pp = s0 + k;
        if (pp < s1) {  // q = k < 64: always chunk 0
            int srcp = __builtin_amdgcn_readlane(eaCur.x, k);
            int cbp = __builtin_amdgcn_readlane(eaCur.y, k);
            hvS[k] = h16c[(size_t)srcp * 64 + lane];
            evS[k] = evt[(size_t)cbp * 64 + lane];
        }
    }

    float accwx = 0.f, accwy = 0.f, accmx = 0.f, accmy = 0.f;
    int cur = 0;
    int nend = __builtin_amdgcn_readlane(rsv, 1);

    // eps folded: weights lose the exp(eps*t) factor (softmax-invariant); aggregated
    // message regains +eps once here (sum(alpha)=1). Empty rows: +1e-7 abs, negligible.
#define CLOSE_ROW()                                                           \
    {                                                                         \
        __half2 hh;                                                           \
        switch (cur) {                                                        \
            case 0: hh = hsv0; break; case 1: hh = hsv1; break;               \
            case 2: hh = hsv2; break; case 3: hh = hsv3; break;               \
            case 4: hh = hsv4; break; case 5: hh = hsv5; break;               \
            case 6: hh = hsv6; break; default: hh = hsv7; break;              \
        }                                                                     \
        f16x2 hvv = h2v(hh);                                                  \
        if (applyBN)                                                          \
            hvv = __builtin_elementwise_max(hvv * bnA2 + bnB2, zerov);        \
        float2 yy;                                                            \
        yy.x = (float)hvv[0] + __fdividef(accmx, accwx + 1e-16f) + 1e-7f;     \
        yy.y = (float)hvv[1] + __fdividef(accmy, accwy + 1e-16f) + 1e-7f;     \
        tile2[(wave * 8 + cur) * 68 + lane] = __floats2half2_rn(yy.x, yy.y);  \
        accwx = accwy = accmx = accmy = 0.f;                                  \
        cur++;                                                                \
        nend = __builtin_amdgcn_readlane(rsv, min(cur + 1, 8));               \
    }

    while (cur < 8 && nend == s0) CLOSE_ROW();  // leading empty rows

    int total = s1 - s0;
    for (int it = 0; it < total; it += PF) {
#pragma unroll
        for (int k = 0; k < PF; ++k) {
            int p = s0 + it + k;
            if (p < s1) {
                f16x2 hv2 = h2v(hvS[k]);
                if (applyBN)
                    hv2 = __builtin_elementwise_max(hv2 * bnA2 + bnB2, zerov);
                f16x2 m2 = __builtin_elementwise_max(hv2 + h2v(evS[k]), zerov);
                float mx = (float)m2[0];
                float my = (float)m2[1];
                float wx = __expf(mx * tsl);
                float wy = __expf(my * tsl);
                accwx += wx; accmx = fmaf(wx, mx, accmx);
                accwy += wy; accmy = fmaf(wy, my, accmy);
                int pp = p + PF;
                if (pp < s1) {
                    if (pp >= c0 + 64) {  // rollover: eaNxt loaded ~64 edges ago, no drain
                        c0 += 64;
                        eaCur = eaNxt;
                        eaNxt = make_int2(0, 0);
                        if (c0 + 64 + lane < s1) eaNxt = csr[c0 + 64 + lane];
                    }
                    int q = pp - c0;
                    int srcp = __builtin_amdgcn_readlane(eaCur.x, q);
                    int cbp = __builtin_amdgcn_readlane(eaCur.y, q);
                    hvS[k] = h16c[(size_t)srcp * 64 + lane];
                    evS[k] = evt[(size_t)cbp * 64 + lane];
                }
                while (cur < 8 && nend == p + 1) CLOSE_ROW();
            }
        }
    }
#undef CLOSE_ROW
    __syncthreads();

    // ---- MFMA matmul: both waves read all 16 tile rows; wave w covers cols w*64.. ----
    int ln = t & 15;
    int quad = (t & 63) >> 4;
    const _Float16* h16in = (const _Float16*)h16c;

    float cs[4] = {0.f, 0.f, 0.f, 0.f};
    float cq[4] = {0.f, 0.f, 0.f, 0.f};
    const _Float16* ap = yh + ln * 136 + quad * 8;
#pragma unroll
    for (int ct = 0; ct < 4; ++ct) {
        int colg = (wave * 4 + ct) * 16 + ln;
        const _Float16* bp = wt + (size_t)colg * 128 + quad * 8;
        f32x4_t c = {0.f, 0.f, 0.f, 0.f};
#pragma unroll
        for (int kk = 0; kk < 4; ++kk) {
            f16x8 av = *(const f16x8*)(ap + kk * 32);
            f16x8 bv = *(const f16x8*)(bp + kk * 32);
            c = __builtin_amdgcn_mfma_f32_16x16x32_f16(av, bv, c, 0, 0, 0);
        }
        float bsv = bias[colg];
#pragma unroll
        for (int reg = 0; reg < 4; ++reg) {
            int r = row0 + quad * 4 + reg;
            if (r < N) {
                long long off = (long long)r * D + colg;
                float o = c[reg] + bsv;
                if (residual) o += (float)h16in[off];
                h16out[off] = (_Float16)o;
                cs[ct] += o; cq[ct] += o * o;
            }
        }
    }

    // ---- BN-stat partials (reuse smem; y tile dead) ----
    __syncthreads();
    float* stats = (float*)smem;
    int grp = wave * 4 + quad;  // 0..7
#pragma unroll
    for (int ct = 0; ct < 4; ++ct) {
        int colg = (wave * 4 + ct) * 16 + ln;
        stats[grp * 256 + colg] = cs[ct];
        stats[grp * 256 + 128 + colg] = cq[ct];
    }
    __syncthreads();
    float ssumA = 0.f, ssumB = 0.f;
#pragma unroll
    for (int g = 0; g < 8; ++g) {
        ssumA += stats[g * 256 + t];
        ssumB += stats[g * 256 + 128 + t];
    }
    partial[(long long)blockIdx.x * 256 + t] = ssumA;
    partial[(long long)blockIdx.x * 256 + 128 + t] = ssumB;
}

// one block per graph: inline BN finalize (reads acc4, 4KB) + BN+relu, mean pool,
// linear head, sigmoid, blend with rf. half2 loads, 4 nodes/iteration.
__global__ void pool_head_kernel(const __half2* __restrict__ h16,
                                 const float* __restrict__ acc4,
                                 const float* __restrict__ gamma,
                                 const float* __restrict__ bnbeta, float invN,
                                 const int* __restrict__ gstart,
                                 const float* __restrict__ fw, const float* __restrict__ fb,
                                 const float* __restrict__ beta, const float* __restrict__ rf,
                                 float* __restrict__ out) {
    __shared__ float redx[256], redy[256];
    __shared__ float sA[128], sB[128];
    int g = blockIdx.x, t = threadIdx.x;
    if (t < 128) {
        float s1 = acc4[t] + acc4[256 + t] + acc4[512 + t] + acc4[768 + t];
        float s2 = acc4[128 + t] + acc4[384 + t] + acc4[640 + t] + acc4[896 + t];
        float mean = s1 * invN;
        float var = s2 * invN - mean * mean;
        float a = rsqrtf(var + 1e-5f) * gamma[t];
        sA[t] = a;
        sB[t] = bnbeta[t] - mean * a;
    }
    __syncthreads();
    int d2 = t & 63, sub = t >> 6;
    int s0 = gstart[g], s1 = gstart[g + 1];
    float2 a2 = make_float2(sA[2 * d2], sA[2 * d2 + 1]);
    float2 b2 = make_float2(sB[2 * d2], sB[2 * d2 + 1]);
    float ax = 0.f, ay = 0.f;
    for (int n = s0 + sub; n < s1; n += 4) {
        f16x2 v = h2v(h16[(size_t)n * 64 + d2]);
        ax += fmaxf((float)v[0] * a2.x + b2.x, 0.f);
        ay += fmaxf((float)v[1] * a2.y + b2.y, 0.f);
    }
    redx[t] = ax; redy[t] = ay;
    __syncthreads();
    if (t < 64) {
        float sx = redx[t] + redx[t + 64] + redx[t + 128] + redx[t + 192];
        float sy = redy[t] + redy[t + 64] + redy[t + 128] + redy[t + 192];
        float v = sx * fw[2 * t] + sy * fw[2 * t + 1];
#pragma unroll
        for (int off = 32; off > 0; off >>= 1) v += __shfl_down(v, off);
        if (t == 0) {
            float c = fmaxf((float)(s1 - s0), 1.f);
            float pred = v / c + fb[0];
            float sig = 1.f / (1.f + __expf(-pred));
            float bb = beta[0];
            out[g] = (1.f - bb) * sig + bb * rf[g];
        }
    }
}

static inline size_t align16(size_t x) { return (x + 15) & ~(size_t)15; }

extern "C" void kernel_launch(void* const* d_in, const int* in_sizes, int n_in,
                              void* d_out, int out_size, void* d_ws, size_t ws_size,
                              hipStream_t stream) {
    const int* x = (const int*)d_in[0];
    const int* edge_index = (const int*)d_in[1];
    const int* edge_attr = (const int*)d_in[2];
    const int* batch = (const int*)d_in[3];
    const float* rf_pred = (const float*)d_in[4];
    const float* atom_emb = (const float*)d_in[5];
    const float* bond_emb = (const float*)d_in[6];
    const float* conv_w = (const float*)d_in[7];
    const float* conv_b = (const float*)d_in[8];
    const float* ts = (const float*)d_in[9];
    const float* gammas = (const float*)d_in[10];
    const float* bn_betas = (const float*)d_in[11];
    const float* final_w = (const float*)d_in[12];
    const float* final_b = (const float*)d_in[13];
    const float* beta = (const float*)d_in[14];
    float* out = (float*)d_out;

    int N = in_sizes[0] / 9;
    int E = in_sizes[1] / 2;
    int G = in_sizes[4];
    int L = in_sizes[9];

    int nTiles = (N + 15) / 16;
    size_t ND = (size_t)N * D;
    size_t accFloats = (size_t)L * 1024;  // per layer: 4 copies x 256

    char* p = (char*)d_ws;
    _Float16* h16_a = (_Float16*)p;  p += align16(ND * 2);
    _Float16* h16_b = (_Float16*)p;  p += align16(ND * 2);
    __half2* evt = (__half2*)p;      p += align16((size_t)512 * 64 * 4);
    _Float16* wt = (_Float16*)p;     p += align16((size_t)L * 16384 * 2);
    float* partial = (float*)p;      p += align16((size_t)256 * nTiles * 4);
    int* gstart = (int*)p;           p += align16((size_t)(G + 1) * 4);
    // acc + deg contiguous: one memset zeroes both
    float* acc = (float*)p;          p += align16(accFloats * 4);
    int* deg = (int*)p;              p += align16((size_t)N * 4);
    int* row_start = (int*)p;        p += align16((size_t)(N + 1) * 4);
    int* cursor = (int*)p;           p += align16((size_t)N * 4);
    int* bsum = (int*)p;             p += align16((size_t)256 * 4);
    int2* csr = (int2*)p;            p += align16((size_t)E * 8);

    int eBlocks = (E + 255) / 256;
    int nb1024 = (N + 1023) / 1024;
    int wtTotal = L * 16384;
    int ndTotal = N * D;
    int smTotal = E + ndTotal + 512 * 64 + wtTotal + N;
    int smBlocks = (smTotal + 255) / 256;
    float invN = 1.0f / (float)N;

    // ---- CSR + atom embedding + tables + graph boundaries ----
    (void)hipMemsetAsync(acc, 0, align16(accFloats * 4) + (size_t)N * 4, stream);
    hist_kernel<<<eBlocks, 256, 0, stream>>>(edge_index, deg, E);
    scanA_kernel<<<nb1024, 256, 0, stream>>>(deg, bsum, N);
    scanC_kernel<<<nb1024, 256, 0, stream>>>(deg, bsum, nb1024, row_start, cursor, N);
    scatter_misc_kernel<<<smBlocks, 256, 0, stream>>>(edge_index, edge_attr, cursor, csr, E,
                                                      x, atom_emb, h16_a, ndTotal,
                                                      bond_emb, evt, conv_w, wt, wtTotal,
                                                      batch, gstart, N, G);

    _Float16* h16c = h16_a;
    _Float16* h16n = h16_b;
    for (int l = 0; l < L; ++l) {
        int applyBN = (l >= 1) ? 1 : 0;
        const float* accPrev = (l >= 1) ? (acc + (size_t)(l - 1) * 1024) : acc;
        const float* gmPrev = (l >= 1) ? (gammas + (size_t)(l - 1) * D) : gammas;
        const float* bbPrev = (l >= 1) ? (bn_betas + (size_t)(l - 1) * D) : bn_betas;
        fused_layer_kernel<<<nTiles, 128, 0, stream>>>(
            (const __half2*)h16c, accPrev, gmPrev, bbPrev, invN, applyBN, ts, l,
            row_start, csr, evt, wt + (size_t)l * 16384, conv_b + (size_t)l * D,
            applyBN, h16n, partial, N);
        bn_stage1_kernel<<<256, 256, 0, stream>>>(partial, nTiles,
                                                  acc + (size_t)l * 1024);
        _Float16* tmp16 = h16c; h16c = h16n; h16n = tmp16;
    }

    pool_head_kernel<<<G, 256, 0, stream>>>(
        (const __half2*)h16c, acc + (size_t)(L - 1) * 1024,
        gammas + (size_t)(L - 1) * D, bn_betas + (size_t)(L - 1) * D, invN,
        gstart, final_w, final_b, beta, rf_pred, out);
}

// Round 7
// 768.584 us; speedup vs baseline: 1.1029x; 1.0051x over previous
//
#include <hip/hip_runtime.h>
#include <hip/hip_fp16.h>
#include <math.h>

#define D 128
#define PF 12

typedef _Float16 f16x8 __attribute__((ext_vector_type(8)));
typedef _Float16 f16x2 __attribute__((ext_vector_type(2)));
typedef float f32x4_t __attribute__((ext_vector_type(4)));

static __device__ __forceinline__ f16x2 h2v(__half2 h) {
    union { __half2 h; f16x2 v; } u; u.h = h; return u.v;
}
static __device__ __forceinline__ __half2 v2h(f16x2 v) {
    union { f16x2 v; __half2 h; } u; u.v = v; return u.h;
}

// ---------------- CSR build (once per call; edge_index is layer-invariant) ----------------

__global__ void hist_kernel(const int* __restrict__ edge_index, int* __restrict__ deg, int E) {
    int e = blockIdx.x * blockDim.x + threadIdx.x;
    if (e >= E) return;
    atomicAdd(&deg[edge_index[E + e]], 1);
}

__global__ void scanA_kernel(const int* __restrict__ deg, int* __restrict__ bsum, int n) {
    __shared__ int red[256];
    int b = blockIdx.x, t = threadIdx.x;
    int base = b * 1024 + t * 4;
    int s = 0;
#pragma unroll
    for (int j = 0; j < 4; ++j)
        if (base + j < n) s += deg[base + j];
    red[t] = s;
    __syncthreads();
    for (int off = 128; off > 0; off >>= 1) {
        if (t < off) red[t] += red[t + off];
        __syncthreads();
    }
    if (t == 0) bsum[b] = red[0];
}

// R19: scanB folded in — each block redundantly scans the <=256 block sums in LDS
// (nb1024 = ceil(N/1024) <= 256 for N <= 262144; here N=100K -> 98 entries).
__global__ void scanC_kernel(const int* __restrict__ deg, const int* __restrict__ bsum,
                             int nb, int* __restrict__ row_start, int* __restrict__ cursor,
                             int n) {
    __shared__ int sh[256];
    __shared__ int sb[256];
    int b = blockIdx.x, t = threadIdx.x;
    sb[t] = (t < nb) ? bsum[t] : 0;
    int base = b * 1024 + t * 4;
    int v[4];
#pragma unroll
    for (int j = 0; j < 4; ++j) v[j] = (base + j < n) ? deg[base + j] : 0;
    int p[4];
    p[0] = 0; p[1] = v[0]; p[2] = v[0] + v[1]; p[3] = v[0] + v[1] + v[2];
    int s = p[3] + v[3];
    sh[t] = s;
    __syncthreads();
    for (int off = 1; off < 256; off <<= 1) {
        int x = (t >= off) ? sh[t - off] : 0;
        int y = (t >= off) ? sb[t - off] : 0;
        __syncthreads();
        sh[t] += x;
        sb[t] += y;
        __syncthreads();
    }
    int boffb = (b == 0) ? 0 : sb[b - 1];
    int off0 = boffb + sh[t] - s;
#pragma unroll
    for (int j = 0; j < 4; ++j)
        if (base + j < n) {
            row_start[base + j] = off0 + p[j];
            cursor[base + j] = off0 + p[j];
        }
    if (base <= n - 1 && n - 1 < base + 4) row_start[n] = off0 + s;
}

// R19: scatter merged with the setup work (atom embed, ev table, Wt transpose, gstart)
// — independent index ranges, one dispatch instead of two.
__global__ void scatter_misc_kernel(const int* __restrict__ edge_index,
                                    const int* __restrict__ edge_attr,
                                    int* __restrict__ cursor, int2* __restrict__ csr, int E,
                                    const int* __restrict__ x, const float* __restrict__ atom_emb,
                                    _Float16* __restrict__ h16, int ndTotal,
                                    const float* __restrict__ bond_emb, __half2* __restrict__ evt,
                                    const float* __restrict__ conv_w, _Float16* __restrict__ wt,
                                    int wtTotal, const int* __restrict__ batch,
                                    int* __restrict__ gstart, int N, int G) {
    int idx = blockIdx.x * blockDim.x + threadIdx.x;
    if (idx < E) {
        int src = edge_index[idx];
        int dst = edge_index[E + idx];
        int pos = atomicAdd(&cursor[dst], 1);
        int a0 = edge_attr[idx * 3], a1 = edge_attr[idx * 3 + 1], a2 = edge_attr[idx * 3 + 2];
        csr[pos] = make_int2(src, a0 | (a1 << 3) | (a2 << 6));
        return;
    }
    idx -= E;
    if (idx < ndTotal) {
        int n = idx >> 7;
        int d = idx & 127;
        float acc = 0.f;
#pragma unroll
        for (int f = 0; f < 9; ++f) {
            int v = x[n * 9 + f];
            acc += atom_emb[(long long)(f * 64 + v) * D + d];
        }
        h16[idx] = (_Float16)acc;
        return;
    }
    idx -= ndTotal;
    if (idx < 512 * 64) {
        int combo = idx >> 6, j = idx & 63;
        int d0 = 2 * j;
        float ex = bond_emb[(combo & 7) * D + d0] +
                   bond_emb[(8 + ((combo >> 3) & 7)) * D + d0] +
                   bond_emb[(16 + ((combo >> 6) & 7)) * D + d0];
        float ey = bond_emb[(combo & 7) * D + d0 + 1] +
                   bond_emb[(8 + ((combo >> 3) & 7)) * D + d0 + 1] +
                   bond_emb[(16 + ((combo >> 6) & 7)) * D + d0 + 1];
        evt[idx] = __floats2half2_rn(ex, ey);
        return;
    }
    int widx = idx - 512 * 64;
    if (widx < wtTotal) {
        int l = widx >> 14;
        int rem = widx & 16383;
        int n = rem >> 7, k = rem & 127;
        wt[widx] = (_Float16)conv_w[(l << 14) + k * 128 + n];
        return;
    }
    int n = widx - wtTotal;
    if (n >= N) return;
    if (n == 0) {
        for (int g = 0; g <= batch[0]; ++g) gstart[g] = 0;
    } else {
        int b0 = batch[n - 1], b1 = batch[n];
        for (int g = b0 + 1; g <= b1; ++g) gstart[g] = n;
    }
    if (n == N - 1) {
        for (int g = batch[N - 1] + 1; g <= G; ++g) gstart[g] = N;
    }
}

// ---------------- model kernels ----------------

// R20: fused writes per-block partials non-atomically (full BW); stage1 does
// coalesced column sums (256 blocks) and atomicAdds into acc4[4][256] -> 65K
// atomics, 64/addr (hist-class contention). Consumers fold acc4 inline.
__global__ void bn_stage1_kernel(const float* __restrict__ partial, int nb,
                                 float* __restrict__ acc4) {
    int b = blockIdx.x, t = threadIdx.x;
    float s = 0.f;
    for (int r = b; r < nb; r += 256)
        s += partial[(long long)r * 256 + t];
    atomicAdd(&acc4[((b & 3) << 8) + t], s);
}

// R11 structure (the measured optimum of this design family). Post-mortems:
// - R15 PF=16 spilled (launch_bounds(128,8) = 64 VGPR cap; WRITE +25MB scratch).
// - R16 exp2f regressed (OCML fixup path; __expf IS the fast path). KEEP __expf.
// - R16 32-bit gather idx regressed (srcp wave-uniform; size_t form keeps addressing
//   SCALAR: saddr + loop-invariant voffset). KEEP size_t.
// - R17 (kept): eps folded out of edge loop (softmax-invariant), __fdividef at close.
// - R19: per-block BN atomics = L2 serialization (-15.6us/layer). REVERTED.
// - R20: BN fold in prologue CONSUMED acc4 before CSR issue -> vmcnt full-drain
//   bubble at block start (+8.2us/layer). R21 FIX: async-split — ISSUE acc4 loads
//   with the self-row gathers, CONSUME after the CSR chunk loads are in flight
//   (FIFO vmcnt: the fold's wait covers only loads issued at/before acc4; CSR and
//   prefetch stay outstanding). Temp acc regs die before the hvS/evS peak.
// Per-layer fused, 128 threads / 2 waves / 16-row tile: dst-centric softmax agg
// (f16 gathers, packed-f16 inline BN, 12-deep pipeline, double-buffered csr chunks
// [FIFO vmcnt], register self rows, write-only row close) -> f16 y-tile in LDS ->
// ONE barrier -> column-split MFMA f16 16x128 @ 128x128 (+bias, +f16 residual,
// fp32 acc) -> f16 output + per-block BN-stat partials.
// segment-max skipped: softmax shift-invariant, msg bounded -> exp can't overflow fp32.
// NOTE (R9): NO global work-stealing counters on multi-XCD CDNA.
__global__ __launch_bounds__(128, 8) void fused_layer_kernel(
        const __half2* __restrict__ h16c,
        const float* __restrict__ accPrev, const float* __restrict__ gammaPrev,
        const float* __restrict__ betaPrev, float invN, int applyBN,
        const float* __restrict__ ts, int l,
        const int* __restrict__ row_start, const int2* __restrict__ csr,
        const __half2* __restrict__ evt,
        const _Float16* __restrict__ wt, const float* __restrict__ bias,
        int residual, _Float16* __restrict__ h16out,
        float* __restrict__ partial, int N) {
    // y tile: 16 rows x 136 halves = 4352 B; stats scratch needs 8 KB -> size 8192
    __shared__ __align__(16) char smem[8192];
    _Float16* yh = (_Float16*)smem;
    __half2* tile2 = (__half2*)smem;  // half2 view: row stride 68

    int t = threadIdx.x;
    int row0 = blockIdx.x * 16;
    int wave = t >> 6;
    int lane = t & 63;
    float tsl = ts[l];
    int a = row0 + wave * 8;  // wave owns rows a..a+7

    f16x2 zerov = (f16x2)(_Float16)0;
    __half2 zero2 = v2h(zerov);

    // ---- issue phase: rsv, acc4 (BN stats), self-rows — all in flight together ----
    int rsv = row_start[min(a + min(lane, 8), N)];

    float2 u0, u1, u2, u3, w0, w1, w2, w3, gm2, bb2;
    if (applyBN) {
        u0 = ((const float2*)(accPrev + 0 * 256))[lane];
        w0 = ((const float2*)(accPrev + 0 * 256 + 128))[lane];
        u1 = ((const float2*)(accPrev + 1 * 256))[lane];
        w1 = ((const float2*)(accPrev + 1 * 256 + 128))[lane];
        u2 = ((const float2*)(accPrev + 2 * 256))[lane];
        w2 = ((const float2*)(accPrev + 2 * 256 + 128))[lane];
        u3 = ((const float2*)(accPrev + 3 * 256))[lane];
        w3 = ((const float2*)(accPrev + 3 * 256 + 128))[lane];
        gm2 = ((const float2*)gammaPrev)[lane];
        bb2 = ((const float2*)betaPrev)[lane];
    }

    __half2 hsv0 = zero2, hsv1 = zero2, hsv2 = zero2, hsv3 = zero2;
    __half2 hsv4 = zero2, hsv5 = zero2, hsv6 = zero2, hsv7 = zero2;
    if (a + 0 < N) hsv0 = h16c[(size_t)(a + 0) * 64 + lane];
    if (a + 1 < N) hsv1 = h16c[(size_t)(a + 1) * 64 + lane];
    if (a + 2 < N) hsv2 = h16c[(size_t)(a + 2) * 64 + lane];
    if (a + 3 < N) hsv3 = h16c[(size_t)(a + 3) * 64 + lane];
    if (a + 4 < N) hsv4 = h16c[(size_t)(a + 4) * 64 + lane];
    if (a + 5 < N) hsv5 = h16c[(size_t)(a + 5) * 64 + lane];
    if (a + 6 < N) hsv6 = h16c[(size_t)(a + 6) * 64 + lane];
    if (a + 7 < N) hsv7 = h16c[(size_t)(a + 7) * 64 + lane];

    int s0 = __builtin_amdgcn_readlane(rsv, 0);
    int s1 = __builtin_amdgcn_readlane(rsv, 8);

    // double-buffered csr chunks: eaCur active, eaNxt in flight
    int c0 = s0;
    int2 eaCur = make_int2(0, 0), eaNxt = make_int2(0, 0);
    if (c0 + lane < s1) eaCur = csr[c0 + lane];
    if (c0 + 64 + lane < s1) eaNxt = csr[c0 + 64 + lane];

    // ---- consume phase: fold BN coeffs now (acc4 landed; CSR loads stay in flight) ----
    f16x2 bnA2 = zerov, bnB2 = zerov;
    if (applyBN) {
        float s1x = u0.x + u1.x + u2.x + u3.x;
        float s1y = u0.y + u1.y + u2.y + u3.y;
        float s2x = w0.x + w1.x + w2.x + w3.x;
        float s2y = w0.y + w1.y + w2.y + w3.y;
        float meanx = s1x * invN, meany = s1y * invN;
        float varx = s2x * invN - meanx * meanx;
        float vary = s2y * invN - meany * meany;
        float ax = rsqrtf(varx + 1e-5f) * gm2.x;
        float ay = rsqrtf(vary + 1e-5f) * gm2.y;
        bnA2[0] = (_Float16)ax; bnA2[1] = (_Float16)ay;
        bnB2[0] = (_Float16)(bb2.x - meanx * ax);
        bnB2[1] = (_Float16)(bb2.y - meany * ay);
    }

    __half2 hvS[PF], evS[PF];
#pragma unroll
    for (int k = 0; k < PF; ++k) {
        int pp = s0 + k;
        if (pp < s1) {  // q = k < 64: always chunk 0
            int srcp = __builtin_amdgcn_readlane(eaCur.x, k);
            int cbp = __builtin_amdgcn_readlane(eaCur.y, k);
            hvS[k] = h16c[(size_t)srcp * 64 + lane];
            evS[k] = evt[(size_t)cbp * 64 + lane];
        }
    }

    float accwx = 0.f, accwy = 0.f, accmx = 0.f, accmy = 0.f;
    int cur = 0;
    int nend = __builtin_amdgcn_readlane(rsv, 1);

    // eps folded: weights lose the exp(eps*t) factor (softmax-invariant); aggregated
    // message regains +eps once here (sum(alpha)=1). Empty rows: +1e-7 abs, negligible.
#define CLOSE_ROW()                                                           \
    {                                                                         \
        __half2 hh;                                                           \
        switch (cur) {                                                        \
            case 0: hh = hsv0; break; case 1: hh = hsv1; break;               \
            case 2: hh = hsv2; break; case 3: hh = hsv3; break;               \
            case 4: hh = hsv4; break; case 5: hh = hsv5; break;               \
            case 6: hh = hsv6; break; default: hh = hsv7; break;              \
        }                                                                     \
        f16x2 hvv = h2v(hh);                                                  \
        if (applyBN)                                                          \
            hvv = __builtin_elementwise_max(hvv * bnA2 + bnB2, zerov);        \
        float2 yy;                                                            \
        yy.x = (float)hvv[0] + __fdividef(accmx, accwx + 1e-16f) + 1e-7f;     \
        yy.y = (float)hvv[1] + __fdividef(accmy, accwy + 1e-16f) + 1e-7f;     \
        tile2[(wave * 8 + cur) * 68 + lane] = __floats2half2_rn(yy.x, yy.y);  \
        accwx = accwy = accmx = accmy = 0.f;                                  \
        cur++;                                                                \
        nend = __builtin_amdgcn_readlane(rsv, min(cur + 1, 8));               \
    }

    while (cur < 8 && nend == s0) CLOSE_ROW();  // leading empty rows

    int total = s1 - s0;
    for (int it = 0; it < total; it += PF) {
#pragma unroll
        for (int k = 0; k < PF; ++k) {
            int p = s0 + it + k;
            if (p < s1) {
                f16x2 hv2 = h2v(hvS[k]);
                if (applyBN)
                    hv2 = __builtin_elementwise_max(hv2 * bnA2 + bnB2, zerov);
                f16x2 m2 = __builtin_elementwise_max(hv2 + h2v(evS[k]), zerov);
                float mx = (float)m2[0];
                float my = (float)m2[1];
                float wx = __expf(mx * tsl);
                float wy = __expf(my * tsl);
                accwx += wx; accmx = fmaf(wx, mx, accmx);
                accwy += wy; accmy = fmaf(wy, my, accmy);
                int pp = p + PF;
                if (pp < s1) {
                    if (pp >= c0 + 64) {  // rollover: eaNxt loaded ~64 edges ago, no drain
                        c0 += 64;
                        eaCur = eaNxt;
                        eaNxt = make_int2(0, 0);
                        if (c0 + 64 + lane < s1) eaNxt = csr[c0 + 64 + lane];
                    }
                    int q = pp - c0;
                    int srcp = __builtin_amdgcn_readlane(eaCur.x, q);
                    int cbp = __builtin_amdgcn_readlane(eaCur.y, q);
                    hvS[k] = h16c[(size_t)srcp * 64 + lane];
                    evS[k] = evt[(size_t)cbp * 64 + lane];
                }
                while (cur < 8 && nend == p + 1) CLOSE_ROW();
            }
        }
    }
#undef CLOSE_ROW
    __syncthreads();

    // ---- MFMA matmul: both waves read all 16 tile rows; wave w covers cols w*64.. ----
    int ln = t & 15;
    int quad = (t & 63) >> 4;
    const _Float16* h16in = (const _Float16*)h16c;

    float cs[4] = {0.f, 0.f, 0.f, 0.f};
    float cq[4] = {0.f, 0.f, 0.f, 0.f};
    const _Float16* ap = yh + ln * 136 + quad * 8;
#pragma unroll
    for (int ct = 0; ct < 4; ++ct) {
        int colg = (wave * 4 + ct) * 16 + ln;
        const _Float16* bp = wt + (size_t)colg * 128 + quad * 8;
        f32x4_t c = {0.f, 0.f, 0.f, 0.f};
#pragma unroll
        for (int kk = 0; kk < 4; ++kk) {
            f16x8 av = *(const f16x8*)(ap + kk * 32);
            f16x8 bv = *(const f16x8*)(bp + kk * 32);
            c = __builtin_amdgcn_mfma_f32_16x16x32_f16(av, bv, c, 0, 0, 0);
        }
        float bsv = bias[colg];
#pragma unroll
        for (int reg = 0; reg < 4; ++reg) {
            int r = row0 + quad * 4 + reg;
            if (r < N) {
                long long off = (long long)r * D + colg;
                float o = c[reg] + bsv;
                if (residual) o += (float)h16in[off];
                h16out[off] = (_Float16)o;
                cs[ct] += o; cq[ct] += o * o;
            }
        }
    }

    // ---- BN-stat partials (reuse smem; y tile dead) ----
    __syncthreads();
    float* stats = (float*)smem;
    int grp = wave * 4 + quad;  // 0..7
#pragma unroll
    for (int ct = 0; ct < 4; ++ct) {
        int colg = (wave * 4 + ct) * 16 + ln;
        stats[grp * 256 + colg] = cs[ct];
        stats[grp * 256 + 128 + colg] = cq[ct];
    }
    __syncthreads();
    float ssumA = 0.f, ssumB = 0.f;
#pragma unroll
    for (int g = 0; g < 8; ++g) {
        ssumA += stats[g * 256 + t];
        ssumB += stats[g * 256 + 128 + t];
    }
    partial[(long long)blockIdx.x * 256 + t] = ssumA;
    partial[(long long)blockIdx.x * 256 + 128 + t] = ssumB;
}

// one block per graph: inline BN finalize (reads acc4, 4KB) + BN+relu, mean pool,
// linear head, sigmoid, blend with rf. half2 loads, 4 nodes/iteration.
__global__ void pool_head_kernel(const __half2* __restrict__ h16,
                                 const float* __restrict__ acc4,
                                 const float* __restrict__ gamma,
                                 const float* __restrict__ bnbeta, float invN,
                                 const int* __restrict__ gstart,
                                 const float* __restrict__ fw, const float* __restrict__ fb,
                                 const float* __restrict__ beta, const float* __restrict__ rf,
                                 float* __restrict__ out) {
    __shared__ float redx[256], redy[256];
    __shared__ float sA[128], sB[128];
    int g = blockIdx.x, t = threadIdx.x;
    if (t < 128) {
        float s1 = acc4[t] + acc4[256 + t] + acc4[512 + t] + acc4[768 + t];
        float s2 = acc4[128 + t] + acc4[384 + t] + acc4[640 + t] + acc4[896 + t];
        float mean = s1 * invN;
        float var = s2 * invN - mean * mean;
        float a = rsqrtf(var + 1e-5f) * gamma[t];
        sA[t] = a;
        sB[t] = bnbeta[t] - mean * a;
    }
    __syncthreads();
    int d2 = t & 63, sub = t >> 6;
    int s0 = gstart[g], s1 = gstart[g + 1];
    float2 a2 = make_float2(sA[2 * d2], sA[2 * d2 + 1]);
    float2 b2 = make_float2(sB[2 * d2], sB[2 * d2 + 1]);
    float ax = 0.f, ay = 0.f;
    for (int n = s0 + sub; n < s1; n += 4) {
        f16x2 v = h2v(h16[(size_t)n * 64 + d2]);
        ax += fmaxf((float)v[0] * a2.x + b2.x, 0.f);
        ay += fmaxf((float)v[1] * a2.y + b2.y, 0.f);
    }
    redx[t] = ax; redy[t] = ay;
    __syncthreads();
    if (t < 64) {
        float sx = redx[t] + redx[t + 64] + redx[t + 128] + redx[t + 192];
        float sy = redy[t] + redy[t + 64] + redy[t + 128] + redy[t + 192];
        float v = sx * fw[2 * t] + sy * fw[2 * t + 1];
#pragma unroll
        for (int off = 32; off > 0; off >>= 1) v += __shfl_down(v, off);
        if (t == 0) {
            float c = fmaxf((float)(s1 - s0), 1.f);
            float pred = v / c + fb[0];
            float sig = 1.f / (1.f + __expf(-pred));
            float bb = beta[0];
            out[g] = (1.f - bb) * sig + bb * rf[g];
        }
    }
}

static inline size_t align16(size_t x) { return (x + 15) & ~(size_t)15; }

extern "C" void kernel_launch(void* const* d_in, const int* in_sizes, int n_in,
                              void* d_out, int out_size, void* d_ws, size_t ws_size,
                              hipStream_t stream) {
    const int* x = (const int*)d_in[0];
    const int* edge_index = (const int*)d_in[1];
    const int* edge_attr = (const int*)d_in[2];
    const int* batch = (const int*)d_in[3];
    const float* rf_pred = (const float*)d_in[4];
    const float* atom_emb = (const float*)d_in[5];
    const float* bond_emb = (const float*)d_in[6];
    const float* conv_w = (const float*)d_in[7];
    const float* conv_b = (const float*)d_in[8];
    const float* ts = (const float*)d_in[9];
    const float* gammas = (const float*)d_in[10];
    const float* bn_betas = (const float*)d_in[11];
    const float* final_w = (const float*)d_in[12];
    const float* final_b = (const float*)d_in[13];
    const float* beta = (const float*)d_in[14];
    float* out = (float*)d_out;

    int N = in_sizes[0] / 9;
    int E = in_sizes[1] / 2;
    int G = in_sizes[4];
    int L = in_sizes[9];

    int nTiles = (N + 15) / 16;
    size_t ND = (size_t)N * D;
    size_t accFloats = (size_t)L * 1024;  // per layer: 4 copies x 256

    char* p = (char*)d_ws;
    _Float16* h16_a = (_Float16*)p;  p += align16(ND * 2);
    _Float16* h16_b = (_Float16*)p;  p += align16(ND * 2);
    __half2* evt = (__half2*)p;      p += align16((size_t)512 * 64 * 4);
    _Float16* wt = (_Float16*)p;     p += align16((size_t)L * 16384 * 2);
    float* partial = (float*)p;      p += align16((size_t)256 * nTiles * 4);
    int* gstart = (int*)p;           p += align16((size_t)(G + 1) * 4);
    // acc + deg contiguous: one memset zeroes both
    float* acc = (float*)p;          p += align16(accFloats * 4);
    int* deg = (int*)p;              p += align16((size_t)N * 4);
    int* row_start = (int*)p;        p += align16((size_t)(N + 1) * 4);
    int* cursor = (int*)p;           p += align16((size_t)N * 4);
    int* bsum = (int*)p;             p += align16((size_t)256 * 4);
    int2* csr = (int2*)p;            p += align16((size_t)E * 8);

    int eBlocks = (E + 255) / 256;
    int nb1024 = (N + 1023) / 1024;
    int wtTotal = L * 16384;
    int ndTotal = N * D;
    int smTotal = E + ndTotal + 512 * 64 + wtTotal + N;
    int smBlocks = (smTotal + 255) / 256;
    float invN = 1.0f / (float)N;

    // ---- CSR + atom embedding + tables + graph boundaries ----
    (void)hipMemsetAsync(acc, 0, align16(accFloats * 4) + (size_t)N * 4, stream);
    hist_kernel<<<eBlocks, 256, 0, stream>>>(edge_index, deg, E);
    scanA_kernel<<<nb1024, 256, 0, stream>>>(deg, bsum, N);
    scanC_kernel<<<nb1024, 256, 0, stream>>>(deg, bsum, nb1024, row_start, cursor, N);
    scatter_misc_kernel<<<smBlocks, 256, 0, stream>>>(edge_index, edge_attr, cursor, csr, E,
                                                      x, atom_emb, h16_a, ndTotal,
                                                      bond_emb, evt, conv_w, wt, wtTotal,
                                                      batch, gstart, N, G);

    _Float16* h16c = h16_a;
    _Float16* h16n = h16_b;
    for (int l = 0; l < L; ++l) {
        int applyBN = (l >= 1) ? 1 : 0;
        const float* accPrev = (l >= 1) ? (acc + (size_t)(l - 1) * 1024) : acc;
        const float* gmPrev = (l >= 1) ? (gammas + (size_t)(l - 1) * D) : gammas;
        const float* bbPrev = (l >= 1) ? (bn_betas + (size_t)(l - 1) * D) : bn_betas;
        fused_layer_kernel<<<nTiles, 128, 0, stream>>>(
            (const __half2*)h16c, accPrev, gmPrev, bbPrev, invN, applyBN, ts, l,
            row_start, csr, evt, wt + (size_t)l * 16384, conv_b + (size_t)l * D,
            applyBN, h16n, partial, N);
        bn_stage1_kernel<<<256, 256, 0, stream>>>(partial, nTiles,
                                                  acc + (size_t)l * 1024);
        _Float16* tmp16 = h16c; h16c = h16n; h16n = tmp16;
    }

    pool_head_kernel<<<G, 256, 0, stream>>>(
        (const __half2*)h16c, acc + (size_t)(L - 1) * 1024,
        gammas + (size_t)(L - 1) * D, bn_betas + (size_t)(L - 1) * D, invN,
        gstart, final_w, final_b, beta, rf_pred, out);
}

// Round 8
// 755.257 us; speedup vs baseline: 1.1224x; 1.0176x over previous
//
#include <hip/hip_runtime.h>
#include <hip/hip_fp16.h>
#include <math.h>

#define D 128
#define PF 12

typedef _Float16 f16x8 __attribute__((ext_vector_type(8)));
typedef _Float16 f16x2 __attribute__((ext_vector_type(2)));
typedef float f32x4_t __attribute__((ext_vector_type(4)));
typedef float f32x2 __attribute__((ext_vector_type(2)));

static __device__ __forceinline__ f16x2 h2v(__half2 h) {
    union { __half2 h; f16x2 v; } u; u.h = h; return u.v;
}
static __device__ __forceinline__ __half2 v2h(f16x2 v) {
    union { f16x2 v; __half2 h; } u; u.v = v; return u.h;
}

// ---------------- CSR build (once per call; edge_index is layer-invariant) ----------------

__global__ void hist_kernel(const int* __restrict__ edge_index, int* __restrict__ deg, int E) {
    int e = blockIdx.x * blockDim.x + threadIdx.x;
    if (e >= E) return;
    atomicAdd(&deg[edge_index[E + e]], 1);
}

__global__ void scanA_kernel(const int* __restrict__ deg, int* __restrict__ bsum, int n) {
    __shared__ int red[256];
    int b = blockIdx.x, t = threadIdx.x;
    int base = b * 1024 + t * 4;
    int s = 0;
#pragma unroll
    for (int j = 0; j < 4; ++j)
        if (base + j < n) s += deg[base + j];
    red[t] = s;
    __syncthreads();
    for (int off = 128; off > 0; off >>= 1) {
        if (t < off) red[t] += red[t + off];
        __syncthreads();
    }
    if (t == 0) bsum[b] = red[0];
}

// R19: scanB folded in — each block redundantly scans the <=256 block sums in LDS
// (nb1024 = ceil(N/1024) <= 256 for N <= 262144; here N=100K -> 98 entries).
__global__ void scanC_kernel(const int* __restrict__ deg, const int* __restrict__ bsum,
                             int nb, int* __restrict__ row_start, int* __restrict__ cursor,
                             int n) {
    __shared__ int sh[256];
    __shared__ int sb[256];
    int b = blockIdx.x, t = threadIdx.x;
    sb[t] = (t < nb) ? bsum[t] : 0;
    int base = b * 1024 + t * 4;
    int v[4];
#pragma unroll
    for (int j = 0; j < 4; ++j) v[j] = (base + j < n) ? deg[base + j] : 0;
    int p[4];
    p[0] = 0; p[1] = v[0]; p[2] = v[0] + v[1]; p[3] = v[0] + v[1] + v[2];
    int s = p[3] + v[3];
    sh[t] = s;
    __syncthreads();
    for (int off = 1; off < 256; off <<= 1) {
        int x = (t >= off) ? sh[t - off] : 0;
        int y = (t >= off) ? sb[t - off] : 0;
        __syncthreads();
        sh[t] += x;
        sb[t] += y;
        __syncthreads();
    }
    int boffb = (b == 0) ? 0 : sb[b - 1];
    int off0 = boffb + sh[t] - s;
#pragma unroll
    for (int j = 0; j < 4; ++j)
        if (base + j < n) {
            row_start[base + j] = off0 + p[j];
            cursor[base + j] = off0 + p[j];
        }
    if (base <= n - 1 && n - 1 < base + 4) row_start[n] = off0 + s;
}

// R19: scatter merged with the setup work. R22: atom embed range now half2-granular
// (2 d's per thread, float2 table loads) — halves its thread count and VALU.
__global__ void scatter_misc_kernel(const int* __restrict__ edge_index,
                                    const int* __restrict__ edge_attr,
                                    int* __restrict__ cursor, int2* __restrict__ csr, int E,
                                    const int* __restrict__ x, const float* __restrict__ atom_emb,
                                    __half2* __restrict__ h16v, int ndHalf,
                                    const float* __restrict__ bond_emb, __half2* __restrict__ evt,
                                    const float* __restrict__ conv_w, _Float16* __restrict__ wt,
                                    int wtTotal, const int* __restrict__ batch,
                                    int* __restrict__ gstart, int N, int G) {
    int idx = blockIdx.x * blockDim.x + threadIdx.x;
    if (idx < E) {
        int src = edge_index[idx];
        int dst = edge_index[E + idx];
        int pos = atomicAdd(&cursor[dst], 1);
        int a0 = edge_attr[idx * 3], a1 = edge_attr[idx * 3 + 1], a2 = edge_attr[idx * 3 + 2];
        csr[pos] = make_int2(src, a0 | (a1 << 3) | (a2 << 6));
        return;
    }
    idx -= E;
    if (idx < ndHalf) {
        int n = idx >> 6;
        int d2 = idx & 63;
        float ax = 0.f, ay = 0.f;
#pragma unroll
        for (int f = 0; f < 9; ++f) {
            int v = x[n * 9 + f];
            float2 e = ((const float2*)atom_emb)[(size_t)(f * 64 + v) * 64 + d2];
            ax += e.x; ay += e.y;
        }
        h16v[idx] = __floats2half2_rn(ax, ay);
        return;
    }
    idx -= ndHalf;
    if (idx < 512 * 64) {
        int combo = idx >> 6, j = idx & 63;
        int d0 = 2 * j;
        float ex = bond_emb[(combo & 7) * D + d0] +
                   bond_emb[(8 + ((combo >> 3) & 7)) * D + d0] +
                   bond_emb[(16 + ((combo >> 6) & 7)) * D + d0];
        float ey = bond_emb[(combo & 7) * D + d0 + 1] +
                   bond_emb[(8 + ((combo >> 3) & 7)) * D + d0 + 1] +
                   bond_emb[(16 + ((combo >> 6) & 7)) * D + d0 + 1];
        evt[idx] = __floats2half2_rn(ex, ey);
        return;
    }
    int widx = idx - 512 * 64;
    if (widx < wtTotal) {
        int l = widx >> 14;
        int rem = widx & 16383;
        int n = rem >> 7, k = rem & 127;
        wt[widx] = (_Float16)conv_w[(l << 14) + k * 128 + n];
        return;
    }
    int n = widx - wtTotal;
    if (n >= N) return;
    if (n == 0) {
        for (int g = 0; g <= batch[0]; ++g) gstart[g] = 0;
    } else {
        int b0 = batch[n - 1], b1 = batch[n];
        for (int g = b0 + 1; g <= b1; ++g) gstart[g] = n;
    }
    if (n == N - 1) {
        for (int g = batch[N - 1] + 1; g <= G; ++g) gstart[g] = N;
    }
}

// ---------------- model kernels ----------------

// R20: fused writes per-block partials non-atomically (full BW); stage1 does
// coalesced column sums (256 blocks) and atomicAdds into acc4[4][256] -> 65K
// atomics, 64/addr (hist-class contention). Consumers fold acc4 inline.
__global__ void bn_stage1_kernel(const float* __restrict__ partial, int nb,
                                 float* __restrict__ acc4) {
    int b = blockIdx.x, t = threadIdx.x;
    float s = 0.f;
    for (int r = b; r < nb; r += 256)
        s += partial[(long long)r * 256 + t];
    atomicAdd(&acc4[((b & 3) << 8) + t], s);
}

// R11 structure (the measured optimum of this design family). Post-mortems:
// - R15 PF=16 spilled (launch_bounds(128,8) = 64 VGPR cap; WRITE +25MB scratch).
// - R16 exp2f (libm) regressed: OCML fixup path. __expf / raw __builtin_amdgcn_exp2f
//   are the fast path (bare v_exp_f32).
// - R16 32-bit gather idx regressed (srcp wave-uniform; size_t form keeps addressing
//   SCALAR: saddr + loop-invariant voffset). KEEP size_t.
// - R17 (kept): eps folded out of edge loop (softmax-invariant), __fdividef at close.
// - R19: per-block BN atomics = L2 serialization. REVERTED. R21 (kept): BN fold
//   async-split in prologue (issue acc4 with self-rows, consume after CSR issue).
// - R22: edge-loop f32 tail PACKED — CDNA4 dual-issues f32 pairs via
//   v_pk_{mul,add,fma}_f32 (clang selects them for float-ext_vector(2) arithmetic).
//   mul2/add2/fma2 -> 1 pk op each; exp via raw exp2 with prescaled t*log2e
//   (bit-identical to __expf's internal mul+exp, now packed). 14 -> ~11 VALU
//   issues/edge. Edge loop is VALU-ISSUE bound (12 cyc/edge measured = issue rate).
// Per-layer fused, 128 threads / 2 waves / 16-row tile: dst-centric softmax agg
// (f16 gathers, packed-f16 inline BN, 12-deep pipeline, double-buffered csr chunks
// [FIFO vmcnt], register self rows, write-only row close) -> f16 y-tile in LDS ->
// ONE barrier -> column-split MFMA f16 16x128 @ 128x128 (+bias, +f16 residual,
// fp32 acc) -> f16 output + per-block BN-stat partials.
// segment-max skipped: softmax shift-invariant, msg bounded -> exp can't overflow fp32.
// NOTE (R9): NO global work-stealing counters on multi-XCD CDNA.
__global__ __launch_bounds__(128, 8) void fused_layer_kernel(
        const __half2* __restrict__ h16c,
        const float* __restrict__ accPrev, const float* __restrict__ gammaPrev,
        const float* __restrict__ betaPrev, float invN, int applyBN,
        const float* __restrict__ ts, int l,
        const int* __restrict__ row_start, const int2* __restrict__ csr,
        const __half2* __restrict__ evt,
        const _Float16* __restrict__ wt, const float* __restrict__ bias,
        int residual, _Float16* __restrict__ h16out,
        float* __restrict__ partial, int N) {
    // y tile: 16 rows x 136 halves = 4352 B; stats scratch needs 8 KB -> size 8192
    __shared__ __align__(16) char smem[8192];
    _Float16* yh = (_Float16*)smem;
    __half2* tile2 = (__half2*)smem;  // half2 view: row stride 68

    int t = threadIdx.x;
    int row0 = blockIdx.x * 16;
    int wave = t >> 6;
    int lane = t & 63;
    float tsl = ts[l];
    f32x2 tse2;
    tse2[0] = tsl * 1.44269504089f;  // fold log2e: __expf(m*t) == exp2(m*(t*log2e))
    tse2[1] = tse2[0];
    int a = row0 + wave * 8;  // wave owns rows a..a+7

    f16x2 zerov = (f16x2)(_Float16)0;
    __half2 zero2 = v2h(zerov);

    // ---- issue phase: rsv, acc4 (BN stats), self-rows — all in flight together ----
    int rsv = row_start[min(a + min(lane, 8), N)];

    float2 u0, u1, u2, u3, w0, w1, w2, w3, gm2, bb2;
    if (applyBN) {
        u0 = ((const float2*)(accPrev + 0 * 256))[lane];
        w0 = ((const float2*)(accPrev + 0 * 256 + 128))[lane];
        u1 = ((const float2*)(accPrev + 1 * 256))[lane];
        w1 = ((const float2*)(accPrev + 1 * 256 + 128))[lane];
        u2 = ((const float2*)(accPrev + 2 * 256))[lane];
        w2 = ((const float2*)(accPrev + 2 * 256 + 128))[lane];
        u3 = ((const float2*)(accPrev + 3 * 256))[lane];
        w3 = ((const float2*)(accPrev + 3 * 256 + 128))[lane];
        gm2 = ((const float2*)gammaPrev)[lane];
        bb2 = ((const float2*)betaPrev)[lane];
    }

    __half2 hsv0 = zero2, hsv1 = zero2, hsv2 = zero2, hsv3 = zero2;
    __half2 hsv4 = zero2, hsv5 = zero2, hsv6 = zero2, hsv7 = zero2;
    if (a + 0 < N) hsv0 = h16c[(size_t)(a + 0) * 64 + lane];
    if (a + 1 < N) hsv1 = h16c[(size_t)(a + 1) * 64 + lane];
    if (a + 2 < N) hsv2 = h16c[(size_t)(a + 2) * 64 + lane];
    if (a + 3 < N) hsv3 = h16c[(size_t)(a + 3) * 64 + lane];
    if (a + 4 < N) hsv4 = h16c[(size_t)(a + 4) * 64 + lane];
    if (a + 5 < N) hsv5 = h16c[(size_t)(a + 5) * 64 + lane];
    if (a + 6 < N) hsv6 = h16c[(size_t)(a + 6) * 64 + lane];
    if (a + 7 < N) hsv7 = h16c[(size_t)(a + 7) * 64 + lane];

    int s0 = __builtin_amdgcn_readlane(rsv, 0);
    int s1 = __builtin_amdgcn_readlane(rsv, 8);

    // double-buffered csr chunks: eaCur active, eaNxt in flight
    int c0 = s0;
    int2 eaCur = make_int2(0, 0), eaNxt = make_int2(0, 0);
    if (c0 + lane < s1) eaCur = csr[c0 + lane];
    if (c0 + 64 + lane < s1) eaNxt = csr[c0 + 64 + lane];

    // ---- consume phase: fold BN coeffs now (acc4 landed; CSR loads stay in flight) ----
    f16x2 bnA2 = zerov, bnB2 = zerov;
    if (applyBN) {
        float s1x = u0.x + u1.x + u2.x + u3.x;
        float s1y = u0.y + u1.y + u2.y + u3.y;
        float s2x = w0.x + w1.x + w2.x + w3.x;
        float s2y = w0.y + w1.y + w2.y + w3.y;
        float meanx = s1x * invN, meany = s1y * invN;
        float varx = s2x * invN - meanx * meanx;
        float vary = s2y * invN - meany * meany;
        float ax = rsqrtf(varx + 1e-5f) * gm2.x;
        float ay = rsqrtf(vary + 1e-5f) * gm2.y;
        bnA2[0] = (_Float16)ax; bnA2[1] = (_Float16)ay;
        bnB2[0] = (_Float16)(bb2.x - meanx * ax);
        bnB2[1] = (_Float16)(bb2.y - meany * ay);
    }

    __half2 hvS[PF], evS[PF];
#pragma unroll
    for (int k = 0; k < PF; ++k) {
        int pp = s0 + k;
        if (pp < s1) {  // q = k < 64: always chunk 0
            int srcp = __builtin_amdgcn_readlane(eaCur.x, k);
            int cbp = __builtin_amdgcn_readlane(eaCur.y, k);
            hvS[k] = h16c[(size_t)srcp * 64 + lane];
            evS[k] = evt[(size_t)cbp * 64 + lane];
        }
    }

    f32x2 accw2 = {0.f, 0.f}, accm2 = {0.f, 0.f};
    int cur = 0;
    int nend = __builtin_amdgcn_readlane(rsv, 1);

    // eps folded: weights lose the exp(eps*t) factor (softmax-invariant); aggregated
    // message regains +eps once here (sum(alpha)=1). Empty rows: +1e-7 abs, negligible.
#define CLOSE_ROW()                                                             \
    {                                                                           \
        __half2 hh;                                                             \
        switch (cur) {                                                          \
            case 0: hh = hsv0; break; case 1: hh = hsv1; break;                 \
            case 2: hh = hsv2; break; case 3: hh = hsv3; break;                 \
            case 4: hh = hsv4; break; case 5: hh = hsv5; break;                 \
            case 6: hh = hsv6; break; default: hh = hsv7; break;                \
        }                                                                       \
        f16x2 hvv = h2v(hh);                                                    \
        if (applyBN)                                                            \
            hvv = __builtin_elementwise_max(hvv * bnA2 + bnB2, zerov);          \
        float2 yy;                                                              \
        yy.x = (float)hvv[0] + __fdividef(accm2[0], accw2[0] + 1e-16f) + 1e-7f; \
        yy.y = (float)hvv[1] + __fdividef(accm2[1], accw2[1] + 1e-16f) + 1e-7f; \
        tile2[(wave * 8 + cur) * 68 + lane] = __floats2half2_rn(yy.x, yy.y);    \
        accw2[0] = 0.f; accw2[1] = 0.f; accm2[0] = 0.f; accm2[1] = 0.f;         \
        cur++;                                                                  \
        nend = __builtin_amdgcn_readlane(rsv, min(cur + 1, 8));                 \
    }

    while (cur < 8 && nend == s0) CLOSE_ROW();  // leading empty rows

    int total = s1 - s0;
    for (int it = 0; it < total; it += PF) {
#pragma unroll
        for (int k = 0; k < PF; ++k) {
            int p = s0 + it + k;
            if (p < s1) {
                f16x2 hv2 = h2v(hvS[k]);
                if (applyBN)
                    hv2 = __builtin_elementwise_max(hv2 * bnA2 + bnB2, zerov);
                f16x2 m2 = __builtin_elementwise_max(hv2 + h2v(evS[k]), zerov);
                f32x2 mf;
                mf[0] = (float)m2[0];
                mf[1] = (float)m2[1];
                f32x2 arg = mf * tse2;  // v_pk_mul_f32
                f32x2 wv;
                wv[0] = __builtin_amdgcn_exp2f(arg[0]);  // raw v_exp_f32
                wv[1] = __builtin_amdgcn_exp2f(arg[1]);
                accw2 += wv;  // v_pk_add_f32
                accm2 = __builtin_elementwise_fma(wv, mf, accm2);  // v_pk_fma_f32
                int pp = p + PF;
                if (pp < s1) {
                    if (pp >= c0 + 64) {  // rollover: eaNxt loaded ~64 edges ago, no drain
                        c0 += 64;
                        eaCur = eaNxt;
                        eaNxt = make_int2(0, 0);
                        if (c0 + 64 + lane < s1) eaNxt = csr[c0 + 64 + lane];
                    }
                    int q = pp - c0;
                    int srcp = __builtin_amdgcn_readlane(eaCur.x, q);
                    int cbp = __builtin_amdgcn_readlane(eaCur.y, q);
                    hvS[k] = h16c[(size_t)srcp * 64 + lane];
                    evS[k] = evt[(size_t)cbp * 64 + lane];
                }
                while (cur < 8 && nend == p + 1) CLOSE_ROW();
            }
        }
    }
#undef CLOSE_ROW
    __syncthreads();

    // ---- MFMA matmul: both waves read all 16 tile rows; wave w covers cols w*64.. ----
    int ln = t & 15;
    int quad = (t & 63) >> 4;
    const _Float16* h16in = (const _Float16*)h16c;

    float cs[4] = {0.f, 0.f, 0.f, 0.f};
    float cq[4] = {0.f, 0.f, 0.f, 0.f};
    const _Float16* ap = yh + ln * 136 + quad * 8;
#pragma unroll
    for (int ct = 0; ct < 4; ++ct) {
        int colg = (wave * 4 + ct) * 16 + ln;
        const _Float16* bp = wt + (size_t)colg * 128 + quad * 8;
        f32x4_t c = {0.f, 0.f, 0.f, 0.f};
#pragma unroll
        for (int kk = 0; kk < 4; ++kk) {
            f16x8 av = *(const f16x8*)(ap + kk * 32);
            f16x8 bv = *(const f16x8*)(bp + kk * 32);
            c = __builtin_amdgcn_mfma_f32_16x16x32_f16(av, bv, c, 0, 0, 0);
        }
        float bsv = bias[colg];
#pragma unroll
        for (int reg = 0; reg < 4; ++reg) {
            int r = row0 + quad * 4 + reg;
            if (r < N) {
                long long off = (long long)r * D + colg;
                float o = c[reg] + bsv;
                if (residual) o += (float)h16in[off];
                h16out[off] = (_Float16)o;
                cs[ct] += o; cq[ct] += o * o;
            }
        }
    }

    // ---- BN-stat partials (reuse smem; y tile dead) ----
    __syncthreads();
    float* stats = (float*)smem;
    int grp = wave * 4 + quad;  // 0..7
#pragma unroll
    for (int ct = 0; ct < 4; ++ct) {
        int colg = (wave * 4 + ct) * 16 + ln;
        stats[grp * 256 + colg] = cs[ct];
        stats[grp * 256 + 128 + colg] = cq[ct];
    }
    __syncthreads();
    float ssumA = 0.f, ssumB = 0.f;
#pragma unroll
    for (int g = 0; g < 8; ++g) {
        ssumA += stats[g * 256 + t];
        ssumB += stats[g * 256 + 128 + t];
    }
    partial[(long long)blockIdx.x * 256 + t] = ssumA;
    partial[(long long)blockIdx.x * 256 + 128 + t] = ssumB;
}

// one block per graph: inline BN finalize (reads acc4, 4KB) + BN+relu, mean pool,
// linear head, sigmoid, blend with rf. half2 loads, 4 nodes/iteration.
__global__ void pool_head_kernel(const __half2* __restrict__ h16,
                                 const float* __restrict__ acc4,
                                 const float* __restrict__ gamma,
                                 const float* __restrict__ bnbeta, float invN,
                                 const int* __restrict__ gstart,
                                 const float* __restrict__ fw, const float* __restrict__ fb,
                                 const float* __restrict__ beta, const float* __restrict__ rf,
                                 float* __restrict__ out) {
    __shared__ float redx[256], redy[256];
    __shared__ float sA[128], sB[128];
    int g = blockIdx.x, t = threadIdx.x;
    if (t < 128) {
        float s1 = acc4[t] + acc4[256 + t] + acc4[512 + t] + acc4[768 + t];
        float s2 = acc4[128 + t] + acc4[384 + t] + acc4[640 + t] + acc4[896 + t];
        float mean = s1 * invN;
        float var = s2 * invN - mean * mean;
        float a = rsqrtf(var + 1e-5f) * gamma[t];
        sA[t] = a;
        sB[t] = bnbeta[t] - mean * a;
    }
    __syncthreads();
    int d2 = t & 63, sub = t >> 6;
    int s0 = gstart[g], s1 = gstart[g + 1];
    float2 a2 = make_float2(sA[2 * d2], sA[2 * d2 + 1]);
    float2 b2 = make_float2(sB[2 * d2], sB[2 * d2 + 1]);
    float ax = 0.f, ay = 0.f;
    for (int n = s0 + sub; n < s1; n += 4) {
        f16x2 v = h2v(h16[(size_t)n * 64 + d2]);
        ax += fmaxf((float)v[0] * a2.x + b2.x, 0.f);
        ay += fmaxf((float)v[1] * a2.y + b2.y, 0.f);
    }
    redx[t] = ax; redy[t] = ay;
    __syncthreads();
    if (t < 64) {
        float sx = redx[t] + redx[t + 64] + redx[t + 128] + redx[t + 192];
        float sy = redy[t] + redy[t + 64] + redy[t + 128] + redy[t + 192];
        float v = sx * fw[2 * t] + sy * fw[2 * t + 1];
#pragma unroll
        for (int off = 32; off > 0; off >>= 1) v += __shfl_down(v, off);
        if (t == 0) {
            float c = fmaxf((float)(s1 - s0), 1.f);
            float pred = v / c + fb[0];
            float sig = 1.f / (1.f + __expf(-pred));
            float bb = beta[0];
            out[g] = (1.f - bb) * sig + bb * rf[g];
        }
    }
}

static inline size_t align16(size_t x) { return (x + 15) & ~(size_t)15; }

extern "C" void kernel_launch(void* const* d_in, const int* in_sizes, int n_in,
                              void* d_out, int out_size, void* d_ws, size_t ws_size,
                              hipStream_t stream) {
    const int* x = (const int*)d_in[0];
    const int* edge_index = (const int*)d_in[1];
    const int* edge_attr = (const int*)d_in[2];
    const int* batch = (const int*)d_in[3];
    const float* rf_pred = (const float*)d_in[4];
    const float* atom_emb = (const float*)d_in[5];
    const float* bond_emb = (const float*)d_in[6];
    const float* conv_w = (const float*)d_in[7];
    const float* conv_b = (const float*)d_in[8];
    const float* ts = (const float*)d_in[9];
    const float* gammas = (const float*)d_in[10];
    const float* bn_betas = (const float*)d_in[11];
    const float* final_w = (const float*)d_in[12];
    const float* final_b = (const float*)d_in[13];
    const float* beta = (const float*)d_in[14];
    float* out = (float*)d_out;

    int N = in_sizes[0] / 9;
    int E = in_sizes[1] / 2;
    int G = in_sizes[4];
    int L = in_sizes[9];

    int nTiles = (N + 15) / 16;
    size_t ND = (size_t)N * D;
    size_t accFloats = (size_t)L * 1024;  // per layer: 4 copies x 256

    char* p = (char*)d_ws;
    _Float16* h16_a = (_Float16*)p;  p += align16(ND * 2);
    _Float16* h16_b = (_Float16*)p;  p += align16(ND * 2);
    __half2* evt = (__half2*)p;      p += align16((size_t)512 * 64 * 4);
    _Float16* wt = (_Float16*)p;     p += align16((size_t)L * 16384 * 2);
    float* partial = (float*)p;      p += align16((size_t)256 * nTiles * 4);
    int* gstart = (int*)p;           p += align16((size_t)(G + 1) * 4);
    // acc + deg contiguous: one memset zeroes both
    float* acc = (float*)p;          p += align16(accFloats * 4);
    int* deg = (int*)p;              p += align16((size_t)N * 4);
    int* row_start = (int*)p;        p += align16((size_t)(N + 1) * 4);
    int* cursor = (int*)p;           p += align16((size_t)N * 4);
    int* bsum = (int*)p;             p += align16((size_t)256 * 4);
    int2* csr = (int2*)p;            p += align16((size_t)E * 8);

    int eBlocks = (E + 255) / 256;
    int nb1024 = (N + 1023) / 1024;
    int wtTotal = L * 16384;
    int ndHalf = N * 64;
    int smTotal = E + ndHalf + 512 * 64 + wtTotal + N;
    int smBlocks = (smTotal + 255) / 256;
    float invN = 1.0f / (float)N;

    // ---- CSR + atom embedding + tables + graph boundaries ----
    (void)hipMemsetAsync(acc, 0, align16(accFloats * 4) + (size_t)N * 4, stream);
    hist_kernel<<<eBlocks, 256, 0, stream>>>(edge_index, deg, E);
    scanA_kernel<<<nb1024, 256, 0, stream>>>(deg, bsum, N);
    scanC_kernel<<<nb1024, 256, 0, stream>>>(deg, bsum, nb1024, row_start, cursor, N);
    scatter_misc_kernel<<<smBlocks, 256, 0, stream>>>(edge_index, edge_attr, cursor, csr, E,
                                                      x, atom_emb, (__half2*)h16_a, ndHalf,
                                                      bond_emb, evt, conv_w, wt, wtTotal,
                                                      batch, gstart, N, G);

    _Float16* h16c = h16_a;
    _Float16* h16n = h16_b;
    for (int l = 0; l < L; ++l) {
        int applyBN = (l >= 1) ? 1 : 0;
        const float* accPrev = (l >= 1) ? (acc + (size_t)(l - 1) * 1024) : acc;
        const float* gmPrev = (l >= 1) ? (gammas + (size_t)(l - 1) * D) : gammas;
        const float* bbPrev = (l >= 1) ? (bn_betas + (size_t)(l - 1) * D) : bn_betas;
        fused_layer_kernel<<<nTiles, 128, 0, stream>>>(
            (const __half2*)h16c, accPrev, gmPrev, bbPrev, invN, applyBN, ts, l,
            row_start, csr, evt, wt + (size_t)l * 16384, conv_b + (size_t)l * D,
            applyBN, h16n, partial, N);
        bn_stage1_kernel<<<256, 256, 0, stream>>>(partial, nTiles,
                                                  acc + (size_t)l * 1024);
        _Float16* tmp16 = h16c; h16c = h16n; h16n = tmp16;
    }

    pool_head_kernel<<<G, 256, 0, stream>>>(
        (const __half2*)h16c, acc + (size_t)(L - 1) * 1024,
        gammas + (size_t)(L - 1) * D, bn_betas + (size_t)(L - 1) * D, invN,
        gstart, final_w, final_b, beta, rf_pred, out);
}